// Round 14
// baseline (1165.730 us; speedup 1.0000x reference)
//
#include <hip/hip_runtime.h>
#include <cstdio>
#include <cmath>

// SE2 multi self-attention forward — R19: byte-identical re-bench of R18 to
// resolve cross-session noise (k_scores, unchanged code, sampled 491/491/529
// across R16/R17/R18 — ±8% chip/clock variance). R18's rest-of-pipeline
// improved 655->632us with the ctx/out K-widening; this round confirms or
// refutes with a second sample. Config: k_scores 64x128 direct + T5 setprio
// (verified +10.6%); ctx/out 64-wide K-tiles (barriers halved); qkv01/qkv_v
// staged-LDS (R15: direct regresses); Pg fp16 P-plane from colred.
// MFMA layouts (gfx950, verified): A[m=lane&15][k=(lane>>4)*8+j],
// B[k=(lane>>4)*8+j][n=lane&15], C/D col=lane&15,row=(lane>>4)*4+reg.

typedef _Float16 h16;
typedef h16 h8 __attribute__((ext_vector_type(8)));
typedef h16 h4 __attribute__((ext_vector_type(4)));
typedef float f4 __attribute__((ext_vector_type(4)));

#define MFMA16(A, B, C) __builtin_amdgcn_mfma_f32_16x16x32_f16(A, B, C, 0, 0, 0)

constexpr int Bb = 4, Mm = 4, Cd = 512, Np = 1024, Nh = 8, Qd = 64;
constexpr float W0 = (float)(2.0 * 3.14159265358979323846 / 1024.0);

// workspace offsets (bytes)
constexpr size_t PL   = 16777216;        // one fp16 plane: 16*512*1024 halves
constexpr size_t QHR = 0, QLR = PL, QHI = 2*PL, QLI = 3*PL;
constexpr size_t KHR = 4*PL, KLR = 5*PL, KHI = 6*PL, KLI = 7*PL;
constexpr size_t SOFF = 8*PL;            // S fp32: 134217728 B (Pg aliases rows)
constexpr size_t XTHR = SOFF, XTLR = SOFF+PL, XTHI = SOFF+2*PL, XTLI = SOFF+3*PL;
constexpr size_t EHR = SOFF+4*PL, ELR = EHR+4194304, EHI = EHR+8388608, ELI = EHR+12582912;
constexpr size_t X2HR = KHR, X2HI = KHR+PL;
constexpr size_t E2HR = KHR+2*PL, E2HI = E2HR+2097152;
constexpr size_t VRO = 0, VIO = PL, CTR = 2*PL, CTI = 3*PL;
// d_out scratch offsets (floats)
constexpr size_t GG_R = 0, GG_I = 131072, WT_C = 262144, WT_S = 266240,
                 CMAX = 270336, CSUM = 303104;

__device__ __forceinline__ unsigned short h2u(h16 h) { return __builtin_bit_cast(unsigned short, h); }
__device__ __forceinline__ void fsplit(float v, h16& h, h16& l) {
    h = (h16)v; l = (h16)(v - (float)h);
}

// ---------------- prep: x -> transposed fp16 planes [bk][n][c] -------------
template <int HIONLY>
__global__ __launch_bounds__(256) void k_prep_x(
    const float* __restrict__ xr, const float* __restrict__ xi,
    h16* __restrict__ phr, h16* __restrict__ plr,
    h16* __restrict__ phi, h16* __restrict__ pli)
{
    __shared__ float T[64][68];
    const int bk = blockIdx.z, N0 = blockIdx.x * 64, C0 = blockIdx.y * 64;
    const int t = threadIdx.x;
    for (int comp = 0; comp < 2; ++comp) {
        const float* src = (comp ? xi : xr) + (size_t)bk * Cd * Np;
        {   // stage x[c][n] tile
            int cc = t >> 2, ch = (t & 3) * 16;
            const float4* s4 = (const float4*)(src + (size_t)(C0 + cc) * Np + N0 + ch);
            float4 a = s4[0], b = s4[1], c = s4[2], d = s4[3];
            float4* dst = (float4*)&T[cc][ch];
            dst[0] = a; dst[1] = b; dst[2] = c; dst[3] = d;
        }
        __syncthreads();
        {   // drain transposed [n][c], split to fp16 hi/lo
            int n = t >> 2, ch = (t & 3) * 16;
            h8 hv0, hv1, lv0, lv1;
#pragma unroll
            for (int jj = 0; jj < 16; ++jj) {
                h16 h, l; fsplit(T[ch + jj][n], h, l);
                if (jj < 8) { hv0[jj] = h; lv0[jj] = l; }
                else        { hv1[jj - 8] = h; lv1[jj - 8] = l; }
            }
            size_t off = (size_t)bk * Np * Cd + (size_t)(N0 + n) * Cd + C0 + ch;
            h16* dh = (comp ? phi : phr) + off;
            *(h8*)dh = hv0; *(h8*)(dh + 8) = hv1;
            if (!HIONLY) {
                h16* dl = (comp ? pli : plr) + off;
                *(h8*)dl = lv0; *(h8*)(dl + 8) = lv1;
            }
        }
        __syncthreads();
    }
}

// ---------------- prep: emb -> fp16 planes (elementwise) -------------------
template <int HIONLY>
__global__ __launch_bounds__(256) void k_prep_emb(
    const float* __restrict__ er, const float* __restrict__ ei, size_t srcbase,
    h16* __restrict__ phr, h16* __restrict__ plr,
    h16* __restrict__ phi, h16* __restrict__ pli)
{
    size_t idx = ((size_t)blockIdx.x * 256 + threadIdx.x) * 4;
    float4 vr = *(const float4*)(er + srcbase + idx);
    float4 vi = *(const float4*)(ei + srcbase + idx);
    h4 hr, lr, hi, li;
    float ar[4] = {vr.x, vr.y, vr.z, vr.w}, ai[4] = {vi.x, vi.y, vi.z, vi.w};
#pragma unroll
    for (int j = 0; j < 4; ++j) {
        h16 h, l; fsplit(ar[j], h, l); hr[j] = h; lr[j] = l;
        fsplit(ai[j], h, l); hi[j] = h; li[j] = l;
    }
    *(h4*)(phr + idx) = hr; *(h4*)(phi + idx) = hi;
    if (!HIONLY) { *(h4*)(plr + idx) = lr; *(h4*)(pli + idx) = li; }
}

// ---------------- wtab: cos/sin(W0*k*j) ------------------------------------
__global__ __launch_bounds__(256) void k_wtab(float* __restrict__ wtc, float* __restrict__ wts)
{
    int idx = blockIdx.x * 256 + threadIdx.x;  // 4096
    int kk = idx >> 10, j = idx & 1023;
    float sn, cs; sincosf(W0 * (float)(kk * j), &sn, &cs);
    wtc[idx] = cs; wts[idx] = sn;
}

// ---------------- k_qkv01: E = emb @ x, split-fp16 MFMA, Q/K out -----------
// R8 staging structure + 2-family accumulators.
__global__ __launch_bounds__(256) void k_qkv01(
    const h16* __restrict__ ehr, const h16* __restrict__ elr,
    const h16* __restrict__ ehi, const h16* __restrict__ eli,
    const h16* __restrict__ xthr, const h16* __restrict__ xtlr,
    const h16* __restrict__ xthi, const h16* __restrict__ xtli,
    h16* __restrict__ qhr, h16* __restrict__ qlr, h16* __restrict__ qhi, h16* __restrict__ qli,
    h16* __restrict__ khr, h16* __restrict__ klr, h16* __restrict__ khi, h16* __restrict__ kli,
    const float* __restrict__ softr, const float* __restrict__ softi)
{
    __shared__ __align__(16) char smem[61440];
    h16* As[4]; h16* Bs[4];
#pragma unroll
    for (int p = 0; p < 4; ++p) { As[p] = (h16*)smem + p * 5120; Bs[p] = (h16*)smem + 20480 + p * 2560; }
    uint* T = (uint*)smem;  // 64 x 132 overlay (epilogue)

    const int t = threadIdx.x;
    const int z = blockIdx.z, e = z >> 4, bk = z & 15, b = bk >> 2, kk = bk & 3;
    const int N0 = blockIdx.x * 64, D0 = blockIdx.y * 128;
    const int wave = t >> 6, lane = t & 63, quad = lane >> 4, l16 = lane & 15;
    const int wy = wave >> 1, wx = wave & 1;

    const h16* APl[4] = { ehr + (size_t)(e * 4 + kk) * 262144, elr + (size_t)(e * 4 + kk) * 262144,
                          ehi + (size_t)(e * 4 + kk) * 262144, eli + (size_t)(e * 4 + kk) * 262144 };
    const h16* BPl[4] = { xthr + (size_t)bk * 524288, xtlr + (size_t)bk * 524288,
                          xthi + (size_t)bk * 524288, xtli + (size_t)bk * 524288 };

    f4 zero = {0.f, 0.f, 0.f, 0.f};
    f4 Er[4][2], Ei[4][2];
#pragma unroll
    for (int r = 0; r < 4; ++r)
#pragma unroll
        for (int c = 0; c < 2; ++c) { Er[r][c] = zero; Ei[r][c] = zero; }

    for (int c0 = 0; c0 < Cd; c0 += 32) {
#pragma unroll
        for (int s = 0; s < 6; ++s) {
            int seg = t + 256 * s;
            const h16* src; h16* dst;
            if (seg < 1024) {
                int p = seg >> 8, rem = seg & 255, row = rem >> 1, ch = rem & 1;
                src = APl[p] + (size_t)(D0 + row) * 512 + c0 + ch * 16;
                dst = As[p] + row * 40 + ch * 16;
            } else {
                int s2 = seg - 1024, p = s2 >> 7, rem = s2 & 127, row = rem >> 1, ch = rem & 1;
                src = BPl[p] + (size_t)(N0 + row) * 512 + c0 + ch * 16;
                dst = Bs[p] + row * 40 + ch * 16;
            }
            const uint4* s4 = (const uint4*)src; uint4 v0 = s4[0], v1 = s4[1];
            uint4* d4 = (uint4*)dst; d4[0] = v0; d4[1] = v1;
        }
        __syncthreads();
        h8 bhr[2], blr[2], bhi[2], bli[2];
#pragma unroll
        for (int cc = 0; cc < 2; ++cc) {
            int o = (wx * 32 + cc * 16 + l16) * 40 + quad * 8;
            bhr[cc] = *(const h8*)(Bs[0] + o); blr[cc] = *(const h8*)(Bs[1] + o);
            bhi[cc] = *(const h8*)(Bs[2] + o); bli[cc] = *(const h8*)(Bs[3] + o);
        }
#pragma unroll
        for (int rr = 0; rr < 4; ++rr) {
            int o = (wy * 64 + rr * 16 + l16) * 40 + quad * 8;
            h8 ahr = *(const h8*)(As[0] + o), alr = *(const h8*)(As[1] + o);
            h8 ahi = *(const h8*)(As[2] + o), ali = *(const h8*)(As[3] + o);
            h8 nhi = -ahi, nli = -ali;
#pragma unroll
            for (int cc = 0; cc < 2; ++cc) {
                Er[rr][cc] = MFMA16(ahr, bhr[cc], Er[rr][cc]);
                Er[rr][cc] = MFMA16(ahr, blr[cc], Er[rr][cc]);
                Er[rr][cc] = MFMA16(alr, bhr[cc], Er[rr][cc]);
                Er[rr][cc] = MFMA16(nhi, bhi[cc], Er[rr][cc]);
                Er[rr][cc] = MFMA16(nhi, bli[cc], Er[rr][cc]);
                Er[rr][cc] = MFMA16(nli, bhi[cc], Er[rr][cc]);
                Ei[rr][cc] = MFMA16(ahr, bhi[cc], Ei[rr][cc]);
                Ei[rr][cc] = MFMA16(ahr, bli[cc], Ei[rr][cc]);
                Ei[rr][cc] = MFMA16(alr, bhi[cc], Ei[rr][cc]);
                Ei[rr][cc] = MFMA16(ahi, bhr[cc], Ei[rr][cc]);
                Ei[rr][cc] = MFMA16(ahi, blr[cc], Ei[rr][cc]);
                Ei[rr][cc] = MFMA16(ali, bhr[cc], Ei[rr][cc]);
            }
        }
        __syncthreads();
    }
    // conj / soft-fold
    f4 ER[4][2], EI[4][2];
#pragma unroll
    for (int rr = 0; rr < 4; ++rr) {
        int h = (D0 + wy * 64 + rr * 16) >> 6;
        float sr = 0.f, si = 0.f;
        if (e == 1) { sr = softr[kk * 8 + h]; si = softi[kk * 8 + h]; }
#pragma unroll
        for (int cc = 0; cc < 2; ++cc) {
            f4 er = Er[rr][cc];
            f4 ei = Ei[rr][cc];
            if (e == 0) { ei = -ei; }                  // Q = conj(E0)
            else { f4 t1 = sr * er - si * ei; ei = sr * ei + si * er; er = t1; }  // K' = soft*K
            ER[rr][cc] = er; EI[rr][cc] = ei;
        }
    }
    const int h0 = D0 >> 6;
    for (int round = 0; round < 2; ++round) {
#pragma unroll
        for (int rr = 0; rr < 4; ++rr)
#pragma unroll
            for (int cc = 0; cc < 2; ++cc)
#pragma unroll
                for (int reg = 0; reg < 4; ++reg) {
                    int dl = wy * 64 + rr * 16 + quad * 4 + reg;
                    int nl = wx * 32 + cc * 16 + l16;
                    float v = round ? EI[rr][cc][reg] : ER[rr][cc][reg];
                    h16 hh, ll; fsplit(v, hh, ll);
                    T[nl * 132 + dl] = ((uint)h2u(hh) << 16) | (uint)h2u(ll);
                }
        __syncthreads();
        {
            int seg = t >> 1, sub = t & 1, n = seg & 63, hh2 = seg >> 6;
            int off = hh2 * 64 + sub * 32;
            uint tmp[32];
            uint4* Tp = (uint4*)&T[n * 132 + off];
#pragma unroll
            for (int w = 0; w < 8; ++w) ((uint4*)tmp)[w] = Tp[w];
            uint hiu[16], lou[16];
#pragma unroll
            for (int w = 0; w < 16; ++w) {
                uint a = tmp[2 * w], b2 = tmp[2 * w + 1];
                hiu[w] = (a >> 16) | (b2 & 0xffff0000u);
                lou[w] = (a & 0xffffu) | (b2 << 16);
            }
            int hg = h0 + hh2;
            size_t dsto = ((size_t)((b * 8 + hg) * 1024 + N0 + n)) * 256 + kk * 64 + sub * 32;
            h16* dh; h16* dl;
            if (round == 0) { dh = (e ? khr : qhr) + dsto; dl = (e ? klr : qlr) + dsto; }
            else            { dh = (e ? khi : qhi) + dsto; dl = (e ? kli : qli) + dsto; }
#pragma unroll
            for (int w = 0; w < 4; ++w) ((uint4*)dh)[w] = ((uint4*)hiu)[w];
#pragma unroll
            for (int w = 0; w < 4; ++w) ((uint4*)dl)[w] = ((uint4*)lou)[w];
        }
        __syncthreads();
    }
}

// ---------------- k_gg: vectorized h8 loads --------------------------------
__global__ __launch_bounds__(256) void k_gg(
    const h16* __restrict__ qhr, const h16* __restrict__ qlr,
    const h16* __restrict__ qhi, const h16* __restrict__ qli,
    const float* __restrict__ encr, const float* __restrict__ enci,
    const float* __restrict__ softr, const float* __restrict__ softi,
    float* __restrict__ ggr, float* __restrict__ ggi)
{
    const int i = blockIdx.x * 256 + threadIdx.x;
    const int z2 = blockIdx.y, kk = z2 & 3, z = z2 >> 2, h = z & 7;
    size_t base = ((size_t)z * 1024 + i) * 256 + kk * 64;
    float gr = 0.f, gi = 0.f;
    const int eb = (kk * 8 + h) * 64;
#pragma unroll
    for (int q8 = 0; q8 < 8; ++q8) {
        h8 vhr = *(const h8*)(qhr + base + q8 * 8);
        h8 vlr = *(const h8*)(qlr + base + q8 * 8);
        h8 vhi = *(const h8*)(qhi + base + q8 * 8);
        h8 vli = *(const h8*)(qli + base + q8 * 8);
#pragma unroll
        for (int j = 0; j < 8; ++j) {
            float qr = (float)vhr[j] + (float)vlr[j];
            float qi = (float)vhi[j] + (float)vli[j];
            float er = encr[eb + q8 * 8 + j], ei = enci[eb + q8 * 8 + j];
            gr = fmaf(qr, er, fmaf(-qi, ei, gr));
            gi = fmaf(qr, ei, fmaf(qi, er, gi));
        }
    }
    float sr = softr[kk * 8 + h], si = softi[kk * 8 + h];
    float tr = gr * sr - gi * si, ti = gr * si + gi * sr;
    float sn, cs; sincosf(W0 * (float)(kk * i), &sn, &cs);
    ggr[(size_t)z2 * 1024 + i] = tr * cs - ti * sn;
    ggi[(size_t)z2 * 1024 + i] = tr * sn + ti * cs;
}

// ---------------- k_scores: direct-global, 64x128 tile + setprio (T5) ------
__global__ __launch_bounds__(256) void k_scores(
    const h16* __restrict__ khr, const h16* __restrict__ klr,
    const h16* __restrict__ khi, const h16* __restrict__ kli,
    const h16* __restrict__ qhr, const h16* __restrict__ qlr,
    const h16* __restrict__ qhi, const h16* __restrict__ qli,
    const float* __restrict__ ggr, const float* __restrict__ ggi,
    const float* __restrict__ wtc, const float* __restrict__ wts,
    float* __restrict__ S)
{
    __shared__ float T[64][68];  // epilogue transpose (one J-half at a time)

    const int t = threadIdx.x, z = blockIdx.z;
    const int I0 = blockIdx.y * 64, J0 = blockIdx.x * 128;
    const int wave = t >> 6, lane = t & 63, quad = lane >> 4, l16 = lane & 15;
    const int wy = wave >> 1, wx = wave & 1;
    const size_t zb = (size_t)z * 262144;
    const h16* Kp0 = khr + zb; const h16* Kp1 = klr + zb;
    const h16* Kp2 = khi + zb; const h16* Kp3 = kli + zb;
    const h16* Qp0 = qhr + zb; const h16* Qp1 = qlr + zb;
    const h16* Qp2 = qhi + zb; const h16* Qp3 = qli + zb;

    int qo[4];
#pragma unroll
    for (int cc = 0; cc < 4; ++cc)
        qo[cc] = (J0 + (cc >> 1) * 64 + wx * 32 + (cc & 1) * 16 + l16) * 256 + quad * 8;
    const int ko0 = (I0 + wy * 32 + l16) * 256 + quad * 8;
    const int ko1 = ko0 + 16 * 256;

    f4 zero = {0.f, 0.f, 0.f, 0.f};
    f4 Sr[2][4], Si[2][4];
#pragma unroll
    for (int r = 0; r < 2; ++r)
#pragma unroll
        for (int c = 0; c < 4; ++c) { Sr[r][c] = zero; Si[r][c] = zero; }

#pragma unroll
    for (int kq0 = 0; kq0 < 256; kq0 += 32) {
        h8 ahr[2], alr[2], ahi[2], ali[2];
#pragma unroll
        for (int rr = 0; rr < 2; ++rr) {
            const int ko = (rr ? ko1 : ko0) + kq0;
            ahr[rr] = *(const h8*)(Kp0 + ko); alr[rr] = *(const h8*)(Kp1 + ko);
            ahi[rr] = *(const h8*)(Kp2 + ko); ali[rr] = *(const h8*)(Kp3 + ko);
        }
#pragma unroll
        for (int cc = 0; cc < 4; ++cc) {
            h8 bhr = *(const h8*)(Qp0 + qo[cc] + kq0);
            h8 blr = *(const h8*)(Qp1 + qo[cc] + kq0);
            h8 bhi = *(const h8*)(Qp2 + qo[cc] + kq0);
            h8 bli = *(const h8*)(Qp3 + qo[cc] + kq0);
            h8 nbhi = -bhi, nbli = -bli;   // transient; (-a)*b == a*(-b)
            __builtin_amdgcn_s_setprio(1);   // T5: favor MFMA-burst wave
#pragma unroll
            for (int rr = 0; rr < 2; ++rr) {
                Sr[rr][cc] = MFMA16(ahr[rr], bhr, Sr[rr][cc]);
                Sr[rr][cc] = MFMA16(ahr[rr], blr, Sr[rr][cc]);
                Sr[rr][cc] = MFMA16(alr[rr], bhr, Sr[rr][cc]);
                Sr[rr][cc] = MFMA16(ahi[rr], nbhi, Sr[rr][cc]);
                Sr[rr][cc] = MFMA16(ahi[rr], nbli, Sr[rr][cc]);
                Sr[rr][cc] = MFMA16(ali[rr], nbhi, Sr[rr][cc]);
                Si[rr][cc] = MFMA16(ahr[rr], bhi, Si[rr][cc]);
                Si[rr][cc] = MFMA16(ahr[rr], bli, Si[rr][cc]);
                Si[rr][cc] = MFMA16(alr[rr], bhi, Si[rr][cc]);
                Si[rr][cc] = MFMA16(ahi[rr], bhr, Si[rr][cc]);
                Si[rr][cc] = MFMA16(ahi[rr], blr, Si[rr][cc]);
                Si[rr][cc] = MFMA16(ali[rr], bhr, Si[rr][cc]);
            }
            __builtin_amdgcn_s_setprio(0);
        }
    }
    // epilogue: + pos, |.|/8, transpose via LDS, write S[z][j][i]; two J-halves
#pragma unroll
    for (int jh = 0; jh < 2; ++jh) {
        if (jh) __syncthreads();
        float wc2[2][4], ws2[2][4];
#pragma unroll
        for (int c = 0; c < 2; ++c) {
            int j = J0 + jh * 64 + wx * 32 + c * 16 + l16;
#pragma unroll
            for (int k = 0; k < 4; ++k) { wc2[c][k] = wtc[k * 1024 + j]; ws2[c][k] = wts[k * 1024 + j]; }
        }
#pragma unroll
        for (int rr = 0; rr < 2; ++rr)
#pragma unroll
            for (int reg = 0; reg < 4; ++reg) {
                int i = I0 + wy * 32 + rr * 16 + quad * 4 + reg;
                float g_r[4], g_i[4];
#pragma unroll
                for (int k = 0; k < 4; ++k) {
                    g_r[k] = ggr[(size_t)(z * 4 + k) * 1024 + i];
                    g_i[k] = ggi[(size_t)(z * 4 + k) * 1024 + i];
                }
#pragma unroll
                for (int c = 0; c < 2; ++c) {
                    int cc = jh * 2 + c;
                    float pr = 0.f, pi = 0.f;
#pragma unroll
                    for (int k = 0; k < 4; ++k) {
                        pr += g_r[k] * wc2[c][k] + g_i[k] * ws2[c][k];
                        pi += g_i[k] * wc2[c][k] - g_r[k] * ws2[c][k];
                    }
                    float ar = Sr[rr][cc][reg] + pr, ai = Si[rr][cc][reg] + pi;
                    int jl = wx * 32 + c * 16 + l16, il = wy * 32 + rr * 16 + quad * 4 + reg;
                    T[jl][il] = sqrtf(ar * ar + ai * ai) * 0.125f;
                }
            }
        __syncthreads();
        {
            int j2 = t >> 2, ch = (t & 3) * 16;
            float4* Tp = (float4*)&T[j2][ch];
            float4* dst = (float4*)(S + ((size_t)z * 1024 + J0 + jh * 64 + j2) * 1024 + I0 + ch);
#pragma unroll
            for (int w = 0; w < 4; ++w) dst[w] = Tp[w];
        }
    }
}

// ---------------- k_colred: row max, expsum, fp16 Pg plane -----------------
__global__ __launch_bounds__(256) void k_colred(
    const float* __restrict__ S, float* __restrict__ cmax, float* __restrict__ csum,
    h16* __restrict__ Pg)
{
    __shared__ float sm[256];
    const int t = threadIdx.x;
    size_t row = blockIdx.x;
    float4 v = ((const float4*)(S + row * 1024))[t];
    float m = fmaxf(fmaxf(v.x, v.y), fmaxf(v.z, v.w));
    sm[t] = m; __syncthreads();
    for (int s = 128; s > 0; s >>= 1) { if (t < s) sm[t] = fmaxf(sm[t], sm[t + s]); __syncthreads(); }
    float M = sm[0]; __syncthreads();
    float e0 = __expf(v.x - M), e1 = __expf(v.y - M), e2 = __expf(v.z - M), e3 = __expf(v.w - M);
    sm[t] = e0 + e1 + e2 + e3; __syncthreads();
    for (int s = 128; s > 0; s >>= 1) { if (t < s) sm[t] += sm[t + s]; __syncthreads(); }
    h4 p; p[0] = (h16)e0; p[1] = (h16)e1; p[2] = (h16)e2; p[3] = (h16)e3;
    *(h4*)(Pg + row * 2048 + t * 4) = p;
    if (t == 0) { cmax[row] = M; csum[row] = sm[0]; }
}

// ---------------- k_qkv_v: V = emb2 @ x (plain fp16 MFMA) ------------------
__global__ __launch_bounds__(256) void k_qkv_v(
    const h16* __restrict__ e2hr, const h16* __restrict__ e2hi,
    const h16* __restrict__ x2hr, const h16* __restrict__ x2hi,
    h16* __restrict__ vr, h16* __restrict__ vi)
{
    __shared__ __align__(16) h16 smem[15360];
    h16* A2[2]; h16* B2[2];
#pragma unroll
    for (int p = 0; p < 2; ++p) { A2[p] = smem + p * 5120; B2[p] = smem + 10240 + p * 2560; }
    const int t = threadIdx.x, bk = blockIdx.z, kk = bk & 3;
    const int N0 = blockIdx.x * 64, D0 = blockIdx.y * 128;
    const int wave = t >> 6, lane = t & 63, quad = lane >> 4, l16 = lane & 15;
    const int wy = wave >> 1, wx = wave & 1;
    const h16* APl[2] = { e2hr + (size_t)kk * 262144, e2hi + (size_t)kk * 262144 };
    const h16* BPl[2] = { x2hr + (size_t)bk * 524288, x2hi + (size_t)bk * 524288 };

    f4 zero = {0.f, 0.f, 0.f, 0.f};
    f4 Rc[4][2], Ic[4][2];
#pragma unroll
    for (int r = 0; r < 4; ++r)
#pragma unroll
        for (int c = 0; c < 2; ++c) { Rc[r][c] = zero; Ic[r][c] = zero; }

    for (int c0 = 0; c0 < Cd; c0 += 32) {
#pragma unroll
        for (int s = 0; s < 3; ++s) {
            int seg = t + 256 * s;
            const h16* src; h16* dst;
            if (seg < 512) {
                int p = seg >> 8, rem = seg & 255, row = rem >> 1, ch = rem & 1;
                src = APl[p] + (size_t)(D0 + row) * 512 + c0 + ch * 16;
                dst = A2[p] + row * 40 + ch * 16;
            } else {
                int s2 = seg - 512, p = s2 >> 7, rem = s2 & 127, row = rem >> 1, ch = rem & 1;
                src = BPl[p] + (size_t)(N0 + row) * 512 + c0 + ch * 16;
                dst = B2[p] + row * 40 + ch * 16;
            }
            const uint4* s4 = (const uint4*)src; uint4 v0 = s4[0], v1 = s4[1];
            uint4* d4 = (uint4*)dst; d4[0] = v0; d4[1] = v1;
        }
        __syncthreads();
        h8 bhr[2], bhi[2];
#pragma unroll
        for (int cc = 0; cc < 2; ++cc) {
            int o = (wx * 32 + cc * 16 + l16) * 40 + quad * 8;
            bhr[cc] = *(const h8*)(B2[0] + o); bhi[cc] = *(const h8*)(B2[1] + o);
        }
#pragma unroll
        for (int rr = 0; rr < 4; ++rr) {
            int o = (wy * 64 + rr * 16 + l16) * 40 + quad * 8;
            h8 ahr = *(const h8*)(A2[0] + o), ahi = *(const h8*)(A2[1] + o);
            h8 nhi = -ahi;
#pragma unroll
            for (int cc = 0; cc < 2; ++cc) {
                Rc[rr][cc] = MFMA16(ahr, bhr[cc], Rc[rr][cc]);
                Rc[rr][cc] = MFMA16(nhi, bhi[cc], Rc[rr][cc]);
                Ic[rr][cc] = MFMA16(ahr, bhi[cc], Ic[rr][cc]);
                Ic[rr][cc] = MFMA16(ahi, bhr[cc], Ic[rr][cc]);
            }
        }
        __syncthreads();
    }
#pragma unroll
    for (int rr = 0; rr < 4; ++rr)
#pragma unroll
        for (int cc = 0; cc < 2; ++cc)
#pragma unroll
            for (int reg = 0; reg < 4; ++reg) {
                int dl = D0 + wy * 64 + rr * 16 + quad * 4 + reg;
                int nl = N0 + wx * 32 + cc * 16 + l16;
                size_t o = (size_t)bk * 524288 + (size_t)dl * 1024 + nl;
                vr[o] = (h16)Rc[rr][cc][reg];
                vi[o] = (h16)Ic[rr][cc][reg];
            }
}

// ---------------- k_ctx: ctx = V @ P, 64-wide i-tiles (R18) ----------------
// Barriers 64->32 per block; same MFMA k-chunk order (bit-identical).
__global__ __launch_bounds__(256) void k_ctx(
    const h16* __restrict__ vr, const h16* __restrict__ vi,
    const h16* __restrict__ Pg, const float* __restrict__ csum,
    h16* __restrict__ ctr, h16* __restrict__ cti)
{
    __shared__ __align__(16) h16 Vsr[4608], Vsi[4608], Ps[4608];  // 64 x 72
    __shared__ __align__(16) h16 T2[4608];  // 64 x 72
    const int t = threadIdx.x, z = blockIdx.z, kk = blockIdx.y, M0 = blockIdx.x * 64;
    const int b = z >> 3, h = z & 7;
    const int wave = t >> 6, lane = t & 63, quad = lane >> 4, l16 = lane & 15;
    const int wy = wave >> 1, wx = wave & 1;
    const size_t vbase = (size_t)(b * 4 + kk) * 524288 + (size_t)(h * 64) * 1024;
    const size_t pbase = (size_t)(z * 1024 + M0);

    f4 zero = {0.f, 0.f, 0.f, 0.f};
    f4 accR[2][2], accI[2][2];
#pragma unroll
    for (int r = 0; r < 2; ++r)
#pragma unroll
        for (int c = 0; c < 2; ++c) { accR[r][c] = zero; accI[r][c] = zero; }

    for (int i0 = 0; i0 < 1024; i0 += 64) {
        if (t < 128) {
            int comp = t >> 6, q = t & 63;
            const h16* src = (comp ? vi : vr) + vbase + (size_t)q * 1024 + i0;
            h16* dst = (comp ? Vsi : Vsr) + q * 72;
            const uint4* s4 = (const uint4*)src;
#pragma unroll
            for (int w = 0; w < 8; ++w) ((uint4*)dst)[w] = s4[w];
        } else {
            int tt = t - 128, m = tt >> 1, ch = tt & 1;
            const h16* sp = Pg + (pbase + m) * 2048 + i0 + ch * 32;
            h16* dst = Ps + m * 72 + ch * 32;
#pragma unroll
            for (int w = 0; w < 4; ++w) ((uint4*)dst)[w] = ((const uint4*)sp)[w];
        }
        __syncthreads();
#pragma unroll
        for (int ks = 0; ks < 2; ++ks) {
            h8 bp[2];
#pragma unroll
            for (int cc = 0; cc < 2; ++cc)
                bp[cc] = *(const h8*)(Ps + (wx * 32 + cc * 16 + l16) * 72 + ks * 32 + quad * 8);
#pragma unroll
            for (int rr = 0; rr < 2; ++rr) {
                int o = (wy * 32 + rr * 16 + l16) * 72 + ks * 32 + quad * 8;
                h8 avr = *(const h8*)(Vsr + o), avi = *(const h8*)(Vsi + o);
#pragma unroll
                for (int cc = 0; cc < 2; ++cc) {
                    accR[rr][cc] = MFMA16(avr, bp[cc], accR[rr][cc]);
                    accI[rr][cc] = MFMA16(avi, bp[cc], accI[rr][cc]);
                }
            }
        }
        __syncthreads();
    }
    for (int round = 0; round < 2; ++round) {
#pragma unroll
        for (int rr = 0; rr < 2; ++rr)
#pragma unroll
            for (int cc = 0; cc < 2; ++cc) {
                int ml = wx * 32 + cc * 16 + l16;
                float inv = 1.0f / csum[(size_t)z * 1024 + M0 + ml];
#pragma unroll
                for (int reg = 0; reg < 4; ++reg) {
                    int ql = wy * 32 + rr * 16 + quad * 4 + reg;
                    float v = (round ? accI[rr][cc][reg] : accR[rr][cc][reg]) * inv;
                    T2[ml * 72 + ql] = (h16)v;
                }
            }
        __syncthreads();
        {
            int m = t >> 2, ch = (t & 3) * 16;
            h8 v0 = *(const h8*)(T2 + m * 72 + ch), v1 = *(const h8*)(T2 + m * 72 + ch + 8);
            h16* dst = (round ? cti : ctr) + (size_t)(b * 4 + kk) * 524288 + (size_t)(M0 + m) * 512 + h * 64 + ch;
            *(h8*)dst = v0; *(h8*)(dst + 8) = v1;
        }
        __syncthreads();
    }
}

// ---------------- k_out: res = Re(out @ ctx), 64-wide c-tiles (R18) --------
// Barriers 32->16 per block; same MFMA k-chunk order (bit-identical).
__global__ __launch_bounds__(256) void k_out(
    const float* __restrict__ outr, const float* __restrict__ outi,
    const h16* __restrict__ ctr, const h16* __restrict__ cti,
    float* __restrict__ res)
{
    __shared__ __align__(16) h16 smem[18432];  // 4 x 64 x 72
    h16* Asr; h16* Asi; h16* Bsr; h16* Bsi;
    Asr = smem; Asi = smem + 4608; Bsr = smem + 9216; Bsi = smem + 13824;
    const int t = threadIdx.x, bk = blockIdx.z, kk = bk & 3;
    const int N0 = blockIdx.x * 64, D0 = blockIdx.y * 64;
    const int wave = t >> 6, lane = t & 63, quad = lane >> 4, l16 = lane & 15;
    const int wy = wave >> 1, wx = wave & 1;

    f4 zero = {0.f, 0.f, 0.f, 0.f};
    f4 P1[2][2], P2[2][2];
#pragma unroll
    for (int r = 0; r < 2; ++r)
#pragma unroll
        for (int c = 0; c < 2; ++c) { P1[r][c] = zero; P2[r][c] = zero; }

    for (int c0 = 0; c0 < Cd; c0 += 64) {
        {   // stage A: out fp32 -> fp16 (32 floats/thread)
            int comp = t >> 7, rem = t & 127, row = rem >> 1, ch = rem & 1;
            const float4* sp = (const float4*)((comp ? outi : outr) + (size_t)kk * 262144 + (size_t)(D0 + row) * 512 + c0 + ch * 32);
            h16* dst = (comp ? Asi : Asr) + row * 72 + ch * 32;
#pragma unroll
            for (int w2 = 0; w2 < 4; ++w2) {
                float4 v0 = sp[w2 * 2], v1 = sp[w2 * 2 + 1];
                h8 hv;
                hv[0] = (h16)v0.x; hv[1] = (h16)v0.y; hv[2] = (h16)v0.z; hv[3] = (h16)v0.w;
                hv[4] = (h16)v1.x; hv[5] = (h16)v1.y; hv[6] = (h16)v1.z; hv[7] = (h16)v1.w;
                *(h8*)(dst + w2 * 8) = hv;
            }
        }
        {   // stage B: ctx_t fp16 copy (32 halves/thread)
            int comp = t >> 7, rem = t & 127, row = rem >> 1, ch = rem & 1;
            const h16* src = (comp ? cti : ctr) + (size_t)bk * 524288 + (size_t)(N0 + row) * 512 + c0 + ch * 32;
            h16* dst = (comp ? Bsi : Bsr) + row * 72 + ch * 32;
#pragma unroll
            for (int w = 0; w < 4; ++w) ((uint4*)dst)[w] = ((const uint4*)src)[w];
        }
        __syncthreads();
#pragma unroll
        for (int ks = 0; ks < 2; ++ks) {
            h8 br[2], bi[2];
#pragma unroll
            for (int cc = 0; cc < 2; ++cc) {
                int o = (wx * 32 + cc * 16 + l16) * 72 + ks * 32 + quad * 8;
                br[cc] = *(const h8*)(Bsr + o); bi[cc] = *(const h8*)(Bsi + o);
            }
#pragma unroll
            for (int rr = 0; rr < 2; ++rr) {
                int o = (wy * 32 + rr * 16 + l16) * 72 + ks * 32 + quad * 8;
                h8 ar = *(const h8*)(Asr + o), ai = *(const h8*)(Asi + o);
#pragma unroll
                for (int cc = 0; cc < 2; ++cc) {
                    P1[rr][cc] = MFMA16(ar, br[cc], P1[rr][cc]);
                    P2[rr][cc] = MFMA16(ai, bi[cc], P2[rr][cc]);
                }
            }
        }
        __syncthreads();
    }
#pragma unroll
    for (int rr = 0; rr < 2; ++rr)
#pragma unroll
        for (int cc = 0; cc < 2; ++cc)
#pragma unroll
            for (int reg = 0; reg < 4; ++reg) {
                int dl = D0 + wy * 32 + rr * 16 + quad * 4 + reg;
                int nl = N0 + wx * 32 + cc * 16 + l16;
                res[(size_t)bk * 524288 + (size_t)dl * 1024 + nl] = P1[rr][cc][reg] - P2[rr][cc][reg];
            }
}

extern "C" void kernel_launch(void* const* d_in, const int* in_sizes, int n_in,
                              void* d_out, int out_size, void* d_ws, size_t ws_size,
                              hipStream_t stream)
{
    const float* xr    = (const float*)d_in[0];
    const float* xi    = (const float*)d_in[1];
    const float* embr  = (const float*)d_in[2];
    const float* embi  = (const float*)d_in[3];
    const float* encr  = (const float*)d_in[4];
    const float* enci  = (const float*)d_in[5];
    const float* softr = (const float*)d_in[6];
    const float* softi = (const float*)d_in[7];
    const float* outr  = (const float*)d_in[8];
    const float* outi  = (const float*)d_in[9];
    float* res = (float*)d_out;
    char* ws   = (char*)d_ws;
    if (ws_size < (size_t)268435456) return;

    h16* qhr = (h16*)(ws + QHR); h16* qlr = (h16*)(ws + QLR);
    h16* qhi = (h16*)(ws + QHI); h16* qli = (h16*)(ws + QLI);
    h16* khr = (h16*)(ws + KHR); h16* klr = (h16*)(ws + KLR);
    h16* khi = (h16*)(ws + KHI); h16* kli = (h16*)(ws + KLI);
    float* S  = (float*)(ws + SOFF);
    h16* Pg   = (h16*)(ws + SOFF);   // fp16 P plane aliases S rows (row-aligned)
    h16* xthr = (h16*)(ws + XTHR); h16* xtlr = (h16*)(ws + XTLR);
    h16* xthi = (h16*)(ws + XTHI); h16* xtli = (h16*)(ws + XTLI);
    h16* ehr = (h16*)(ws + EHR); h16* elr = (h16*)(ws + ELR);
    h16* ehi = (h16*)(ws + EHI); h16* eli = (h16*)(ws + ELI);
    h16* x2hr = (h16*)(ws + X2HR); h16* x2hi = (h16*)(ws + X2HI);
    h16* e2hr = (h16*)(ws + E2HR); h16* e2hi = (h16*)(ws + E2HI);
    h16* vr = (h16*)(ws + VRO); h16* vi = (h16*)(ws + VIO);
    h16* ctr = (h16*)(ws + CTR); h16* cti = (h16*)(ws + CTI);
    float* sc = (float*)d_out;  // scratch in d_out, overwritten by k_out last
    float* ggr = sc + GG_R; float* ggi = sc + GG_I;
    float* wtc = sc + WT_C; float* wts = sc + WT_S;
    float* cmax = sc + CMAX; float* csum = sc + CSUM;

    k_prep_x<0><<<dim3(16, 8, 16), 256, 0, stream>>>(xr, xi, xthr, xtlr, xthi, xtli);
    k_prep_emb<0><<<dim3(2048), 256, 0, stream>>>(embr, embi, 0, ehr, elr, ehi, eli);
    k_wtab<<<dim3(16), 256, 0, stream>>>(wtc, wts);
    k_qkv01<<<dim3(16, 4, 32), 256, 0, stream>>>(ehr, elr, ehi, eli, xthr, xtlr, xthi, xtli,
                                                 qhr, qlr, qhi, qli, khr, klr, khi, kli, softr, softi);
    k_gg<<<dim3(4, 128), 256, 0, stream>>>(qhr, qlr, qhi, qli, encr, enci, softr, softi, ggr, ggi);
    k_scores<<<dim3(8, 16, 32), 256, 0, stream>>>(khr, klr, khi, kli, qhr, qlr, qhi, qli,
                                                  ggr, ggi, wtc, wts, S);
    k_colred<<<dim3(32768), 256, 0, stream>>>(S, cmax, csum, Pg);
    k_prep_x<1><<<dim3(16, 8, 16), 256, 0, stream>>>(xr, xi, x2hr, x2hr, x2hi, x2hi);
    k_prep_emb<1><<<dim3(1024), 256, 0, stream>>>(embr, embi, 2097152, e2hr, e2hr, e2hi, e2hi);
    k_qkv_v<<<dim3(16, 4, 16), 256, 0, stream>>>(e2hr, e2hi, x2hr, x2hi, vr, vi);
    k_ctx<<<dim3(16, 4, 32), 256, 0, stream>>>(vr, vi, Pg, csum, ctr, cti);
    k_out<<<dim3(16, 8, 16), 256, 0, stream>>>(outr, outi, ctr, cti, res);
}

// Round 15
// 1147.858 us; speedup vs baseline: 1.0156x; 1.0156x over previous
//
#include <hip/hip_runtime.h>
#include <cstdio>
#include <cmath>

// SE2 multi self-attention forward — R20: byte-identical restore of R16, the
// verified champion (1146.7us; corroborated 1150.3 in R17). R18/R19 showed
// the ctx/out K-widening perturbs k_scores codegen via co-compilation
// (rule #19: k_scores 491/491 narrow vs 530/530 wide, same VGPR) for a net
// loss — reverted. Final config: k_scores 64x128 direct-global + T5 setprio
// (+10.6% verified); qkv01/qkv_v/ctx/out staged-LDS 32-wide (R15: direct
// regresses on 1KB-stride planes); colred writes fp16 Pg plane (exp 1x);
// 2-family complex accumulators everywhere.
// MFMA layouts (gfx950, verified): A[m=lane&15][k=(lane>>4)*8+j],
// B[k=(lane>>4)*8+j][n=lane&15], C/D col=lane&15,row=(lane>>4)*4+reg.

typedef _Float16 h16;
typedef h16 h8 __attribute__((ext_vector_type(8)));
typedef h16 h4 __attribute__((ext_vector_type(4)));
typedef float f4 __attribute__((ext_vector_type(4)));

#define MFMA16(A, B, C) __builtin_amdgcn_mfma_f32_16x16x32_f16(A, B, C, 0, 0, 0)

constexpr int Bb = 4, Mm = 4, Cd = 512, Np = 1024, Nh = 8, Qd = 64;
constexpr float W0 = (float)(2.0 * 3.14159265358979323846 / 1024.0);

// workspace offsets (bytes)
constexpr size_t PL   = 16777216;        // one fp16 plane: 16*512*1024 halves
constexpr size_t QHR = 0, QLR = PL, QHI = 2*PL, QLI = 3*PL;
constexpr size_t KHR = 4*PL, KLR = 5*PL, KHI = 6*PL, KLI = 7*PL;
constexpr size_t SOFF = 8*PL;            // S fp32: 134217728 B (Pg aliases rows)
constexpr size_t XTHR = SOFF, XTLR = SOFF+PL, XTHI = SOFF+2*PL, XTLI = SOFF+3*PL;
constexpr size_t EHR = SOFF+4*PL, ELR = EHR+4194304, EHI = EHR+8388608, ELI = EHR+12582912;
constexpr size_t X2HR = KHR, X2HI = KHR+PL;
constexpr size_t E2HR = KHR+2*PL, E2HI = E2HR+2097152;
constexpr size_t VRO = 0, VIO = PL, CTR = 2*PL, CTI = 3*PL;
// d_out scratch offsets (floats)
constexpr size_t GG_R = 0, GG_I = 131072, WT_C = 262144, WT_S = 266240,
                 CMAX = 270336, CSUM = 303104;

__device__ __forceinline__ unsigned short h2u(h16 h) { return __builtin_bit_cast(unsigned short, h); }
__device__ __forceinline__ void fsplit(float v, h16& h, h16& l) {
    h = (h16)v; l = (h16)(v - (float)h);
}

// ---------------- prep: x -> transposed fp16 planes [bk][n][c] -------------
template <int HIONLY>
__global__ __launch_bounds__(256) void k_prep_x(
    const float* __restrict__ xr, const float* __restrict__ xi,
    h16* __restrict__ phr, h16* __restrict__ plr,
    h16* __restrict__ phi, h16* __restrict__ pli)
{
    __shared__ float T[64][68];
    const int bk = blockIdx.z, N0 = blockIdx.x * 64, C0 = blockIdx.y * 64;
    const int t = threadIdx.x;
    for (int comp = 0; comp < 2; ++comp) {
        const float* src = (comp ? xi : xr) + (size_t)bk * Cd * Np;
        {   // stage x[c][n] tile
            int cc = t >> 2, ch = (t & 3) * 16;
            const float4* s4 = (const float4*)(src + (size_t)(C0 + cc) * Np + N0 + ch);
            float4 a = s4[0], b = s4[1], c = s4[2], d = s4[3];
            float4* dst = (float4*)&T[cc][ch];
            dst[0] = a; dst[1] = b; dst[2] = c; dst[3] = d;
        }
        __syncthreads();
        {   // drain transposed [n][c], split to fp16 hi/lo
            int n = t >> 2, ch = (t & 3) * 16;
            h8 hv0, hv1, lv0, lv1;
#pragma unroll
            for (int jj = 0; jj < 16; ++jj) {
                h16 h, l; fsplit(T[ch + jj][n], h, l);
                if (jj < 8) { hv0[jj] = h; lv0[jj] = l; }
                else        { hv1[jj - 8] = h; lv1[jj - 8] = l; }
            }
            size_t off = (size_t)bk * Np * Cd + (size_t)(N0 + n) * Cd + C0 + ch;
            h16* dh = (comp ? phi : phr) + off;
            *(h8*)dh = hv0; *(h8*)(dh + 8) = hv1;
            if (!HIONLY) {
                h16* dl = (comp ? pli : plr) + off;
                *(h8*)dl = lv0; *(h8*)(dl + 8) = lv1;
            }
        }
        __syncthreads();
    }
}

// ---------------- prep: emb -> fp16 planes (elementwise) -------------------
template <int HIONLY>
__global__ __launch_bounds__(256) void k_prep_emb(
    const float* __restrict__ er, const float* __restrict__ ei, size_t srcbase,
    h16* __restrict__ phr, h16* __restrict__ plr,
    h16* __restrict__ phi, h16* __restrict__ pli)
{
    size_t idx = ((size_t)blockIdx.x * 256 + threadIdx.x) * 4;
    float4 vr = *(const float4*)(er + srcbase + idx);
    float4 vi = *(const float4*)(ei + srcbase + idx);
    h4 hr, lr, hi, li;
    float ar[4] = {vr.x, vr.y, vr.z, vr.w}, ai[4] = {vi.x, vi.y, vi.z, vi.w};
#pragma unroll
    for (int j = 0; j < 4; ++j) {
        h16 h, l; fsplit(ar[j], h, l); hr[j] = h; lr[j] = l;
        fsplit(ai[j], h, l); hi[j] = h; li[j] = l;
    }
    *(h4*)(phr + idx) = hr; *(h4*)(phi + idx) = hi;
    if (!HIONLY) { *(h4*)(plr + idx) = lr; *(h4*)(pli + idx) = li; }
}

// ---------------- wtab: cos/sin(W0*k*j) ------------------------------------
__global__ __launch_bounds__(256) void k_wtab(float* __restrict__ wtc, float* __restrict__ wts)
{
    int idx = blockIdx.x * 256 + threadIdx.x;  // 4096
    int kk = idx >> 10, j = idx & 1023;
    float sn, cs; sincosf(W0 * (float)(kk * j), &sn, &cs);
    wtc[idx] = cs; wts[idx] = sn;
}

// ---------------- k_qkv01: E = emb @ x, split-fp16 MFMA, Q/K out -----------
// R8 staging structure + 2-family accumulators (R15 showed direct regresses).
__global__ __launch_bounds__(256) void k_qkv01(
    const h16* __restrict__ ehr, const h16* __restrict__ elr,
    const h16* __restrict__ ehi, const h16* __restrict__ eli,
    const h16* __restrict__ xthr, const h16* __restrict__ xtlr,
    const h16* __restrict__ xthi, const h16* __restrict__ xtli,
    h16* __restrict__ qhr, h16* __restrict__ qlr, h16* __restrict__ qhi, h16* __restrict__ qli,
    h16* __restrict__ khr, h16* __restrict__ klr, h16* __restrict__ khi, h16* __restrict__ kli,
    const float* __restrict__ softr, const float* __restrict__ softi)
{
    __shared__ __align__(16) char smem[61440];
    h16* As[4]; h16* Bs[4];
#pragma unroll
    for (int p = 0; p < 4; ++p) { As[p] = (h16*)smem + p * 5120; Bs[p] = (h16*)smem + 20480 + p * 2560; }
    uint* T = (uint*)smem;  // 64 x 132 overlay (epilogue)

    const int t = threadIdx.x;
    const int z = blockIdx.z, e = z >> 4, bk = z & 15, b = bk >> 2, kk = bk & 3;
    const int N0 = blockIdx.x * 64, D0 = blockIdx.y * 128;
    const int wave = t >> 6, lane = t & 63, quad = lane >> 4, l16 = lane & 15;
    const int wy = wave >> 1, wx = wave & 1;

    const h16* APl[4] = { ehr + (size_t)(e * 4 + kk) * 262144, elr + (size_t)(e * 4 + kk) * 262144,
                          ehi + (size_t)(e * 4 + kk) * 262144, eli + (size_t)(e * 4 + kk) * 262144 };
    const h16* BPl[4] = { xthr + (size_t)bk * 524288, xtlr + (size_t)bk * 524288,
                          xthi + (size_t)bk * 524288, xtli + (size_t)bk * 524288 };

    f4 zero = {0.f, 0.f, 0.f, 0.f};
    f4 Er[4][2], Ei[4][2];
#pragma unroll
    for (int r = 0; r < 4; ++r)
#pragma unroll
        for (int c = 0; c < 2; ++c) { Er[r][c] = zero; Ei[r][c] = zero; }

    for (int c0 = 0; c0 < Cd; c0 += 32) {
#pragma unroll
        for (int s = 0; s < 6; ++s) {
            int seg = t + 256 * s;
            const h16* src; h16* dst;
            if (seg < 1024) {
                int p = seg >> 8, rem = seg & 255, row = rem >> 1, ch = rem & 1;
                src = APl[p] + (size_t)(D0 + row) * 512 + c0 + ch * 16;
                dst = As[p] + row * 40 + ch * 16;
            } else {
                int s2 = seg - 1024, p = s2 >> 7, rem = s2 & 127, row = rem >> 1, ch = rem & 1;
                src = BPl[p] + (size_t)(N0 + row) * 512 + c0 + ch * 16;
                dst = Bs[p] + row * 40 + ch * 16;
            }
            const uint4* s4 = (const uint4*)src; uint4 v0 = s4[0], v1 = s4[1];
            uint4* d4 = (uint4*)dst; d4[0] = v0; d4[1] = v1;
        }
        __syncthreads();
        h8 bhr[2], blr[2], bhi[2], bli[2];
#pragma unroll
        for (int cc = 0; cc < 2; ++cc) {
            int o = (wx * 32 + cc * 16 + l16) * 40 + quad * 8;
            bhr[cc] = *(const h8*)(Bs[0] + o); blr[cc] = *(const h8*)(Bs[1] + o);
            bhi[cc] = *(const h8*)(Bs[2] + o); bli[cc] = *(const h8*)(Bs[3] + o);
        }
#pragma unroll
        for (int rr = 0; rr < 4; ++rr) {
            int o = (wy * 64 + rr * 16 + l16) * 40 + quad * 8;
            h8 ahr = *(const h8*)(As[0] + o), alr = *(const h8*)(As[1] + o);
            h8 ahi = *(const h8*)(As[2] + o), ali = *(const h8*)(As[3] + o);
            h8 nhi = -ahi, nli = -ali;
#pragma unroll
            for (int cc = 0; cc < 2; ++cc) {
                Er[rr][cc] = MFMA16(ahr, bhr[cc], Er[rr][cc]);
                Er[rr][cc] = MFMA16(ahr, blr[cc], Er[rr][cc]);
                Er[rr][cc] = MFMA16(alr, bhr[cc], Er[rr][cc]);
                Er[rr][cc] = MFMA16(nhi, bhi[cc], Er[rr][cc]);
                Er[rr][cc] = MFMA16(nhi, bli[cc], Er[rr][cc]);
                Er[rr][cc] = MFMA16(nli, bhi[cc], Er[rr][cc]);
                Ei[rr][cc] = MFMA16(ahr, bhi[cc], Ei[rr][cc]);
                Ei[rr][cc] = MFMA16(ahr, bli[cc], Ei[rr][cc]);
                Ei[rr][cc] = MFMA16(alr, bhi[cc], Ei[rr][cc]);
                Ei[rr][cc] = MFMA16(ahi, bhr[cc], Ei[rr][cc]);
                Ei[rr][cc] = MFMA16(ahi, blr[cc], Ei[rr][cc]);
                Ei[rr][cc] = MFMA16(ali, bhr[cc], Ei[rr][cc]);
            }
        }
        __syncthreads();
    }
    // conj / soft-fold
    f4 ER[4][2], EI[4][2];
#pragma unroll
    for (int rr = 0; rr < 4; ++rr) {
        int h = (D0 + wy * 64 + rr * 16) >> 6;
        float sr = 0.f, si = 0.f;
        if (e == 1) { sr = softr[kk * 8 + h]; si = softi[kk * 8 + h]; }
#pragma unroll
        for (int cc = 0; cc < 2; ++cc) {
            f4 er = Er[rr][cc];
            f4 ei = Ei[rr][cc];
            if (e == 0) { ei = -ei; }                  // Q = conj(E0)
            else { f4 t1 = sr * er - si * ei; ei = sr * ei + si * er; er = t1; }  // K' = soft*K
            ER[rr][cc] = er; EI[rr][cc] = ei;
        }
    }
    const int h0 = D0 >> 6;
    for (int round = 0; round < 2; ++round) {
#pragma unroll
        for (int rr = 0; rr < 4; ++rr)
#pragma unroll
            for (int cc = 0; cc < 2; ++cc)
#pragma unroll
                for (int reg = 0; reg < 4; ++reg) {
                    int dl = wy * 64 + rr * 16 + quad * 4 + reg;
                    int nl = wx * 32 + cc * 16 + l16;
                    float v = round ? EI[rr][cc][reg] : ER[rr][cc][reg];
                    h16 hh, ll; fsplit(v, hh, ll);
                    T[nl * 132 + dl] = ((uint)h2u(hh) << 16) | (uint)h2u(ll);
                }
        __syncthreads();
        {
            int seg = t >> 1, sub = t & 1, n = seg & 63, hh2 = seg >> 6;
            int off = hh2 * 64 + sub * 32;
            uint tmp[32];
            uint4* Tp = (uint4*)&T[n * 132 + off];
#pragma unroll
            for (int w = 0; w < 8; ++w) ((uint4*)tmp)[w] = Tp[w];
            uint hiu[16], lou[16];
#pragma unroll
            for (int w = 0; w < 16; ++w) {
                uint a = tmp[2 * w], b2 = tmp[2 * w + 1];
                hiu[w] = (a >> 16) | (b2 & 0xffff0000u);
                lou[w] = (a & 0xffffu) | (b2 << 16);
            }
            int hg = h0 + hh2;
            size_t dsto = ((size_t)((b * 8 + hg) * 1024 + N0 + n)) * 256 + kk * 64 + sub * 32;
            h16* dh; h16* dl;
            if (round == 0) { dh = (e ? khr : qhr) + dsto; dl = (e ? klr : qlr) + dsto; }
            else            { dh = (e ? khi : qhi) + dsto; dl = (e ? kli : qli) + dsto; }
#pragma unroll
            for (int w = 0; w < 4; ++w) ((uint4*)dh)[w] = ((uint4*)hiu)[w];
#pragma unroll
            for (int w = 0; w < 4; ++w) ((uint4*)dl)[w] = ((uint4*)lou)[w];
        }
        __syncthreads();
    }
}

// ---------------- k_gg: vectorized h8 loads --------------------------------
__global__ __launch_bounds__(256) void k_gg(
    const h16* __restrict__ qhr, const h16* __restrict__ qlr,
    const h16* __restrict__ qhi, const h16* __restrict__ qli,
    const float* __restrict__ encr, const float* __restrict__ enci,
    const float* __restrict__ softr, const float* __restrict__ softi,
    float* __restrict__ ggr, float* __restrict__ ggi)
{
    const int i = blockIdx.x * 256 + threadIdx.x;
    const int z2 = blockIdx.y, kk = z2 & 3, z = z2 >> 2, h = z & 7;
    size_t base = ((size_t)z * 1024 + i) * 256 + kk * 64;
    float gr = 0.f, gi = 0.f;
    const int eb = (kk * 8 + h) * 64;
#pragma unroll
    for (int q8 = 0; q8 < 8; ++q8) {
        h8 vhr = *(const h8*)(qhr + base + q8 * 8);
        h8 vlr = *(const h8*)(qlr + base + q8 * 8);
        h8 vhi = *(const h8*)(qhi + base + q8 * 8);
        h8 vli = *(const h8*)(qli + base + q8 * 8);
#pragma unroll
        for (int j = 0; j < 8; ++j) {
            float qr = (float)vhr[j] + (float)vlr[j];
            float qi = (float)vhi[j] + (float)vli[j];
            float er = encr[eb + q8 * 8 + j], ei = enci[eb + q8 * 8 + j];
            gr = fmaf(qr, er, fmaf(-qi, ei, gr));
            gi = fmaf(qr, ei, fmaf(qi, er, gi));
        }
    }
    float sr = softr[kk * 8 + h], si = softi[kk * 8 + h];
    float tr = gr * sr - gi * si, ti = gr * si + gi * sr;
    float sn, cs; sincosf(W0 * (float)(kk * i), &sn, &cs);
    ggr[(size_t)z2 * 1024 + i] = tr * cs - ti * sn;
    ggi[(size_t)z2 * 1024 + i] = tr * sn + ti * cs;
}

// ---------------- k_scores: direct-global, 64x128 tile + setprio (T5) ------
__global__ __launch_bounds__(256) void k_scores(
    const h16* __restrict__ khr, const h16* __restrict__ klr,
    const h16* __restrict__ khi, const h16* __restrict__ kli,
    const h16* __restrict__ qhr, const h16* __restrict__ qlr,
    const h16* __restrict__ qhi, const h16* __restrict__ qli,
    const float* __restrict__ ggr, const float* __restrict__ ggi,
    const float* __restrict__ wtc, const float* __restrict__ wts,
    float* __restrict__ S)
{
    __shared__ float T[64][68];  // epilogue transpose (one J-half at a time)

    const int t = threadIdx.x, z = blockIdx.z;
    const int I0 = blockIdx.y * 64, J0 = blockIdx.x * 128;
    const int wave = t >> 6, lane = t & 63, quad = lane >> 4, l16 = lane & 15;
    const int wy = wave >> 1, wx = wave & 1;
    const size_t zb = (size_t)z * 262144;
    const h16* Kp0 = khr + zb; const h16* Kp1 = klr + zb;
    const h16* Kp2 = khi + zb; const h16* Kp3 = kli + zb;
    const h16* Qp0 = qhr + zb; const h16* Qp1 = qlr + zb;
    const h16* Qp2 = qhi + zb; const h16* Qp3 = qli + zb;

    int qo[4];
#pragma unroll
    for (int cc = 0; cc < 4; ++cc)
        qo[cc] = (J0 + (cc >> 1) * 64 + wx * 32 + (cc & 1) * 16 + l16) * 256 + quad * 8;
    const int ko0 = (I0 + wy * 32 + l16) * 256 + quad * 8;
    const int ko1 = ko0 + 16 * 256;

    f4 zero = {0.f, 0.f, 0.f, 0.f};
    f4 Sr[2][4], Si[2][4];
#pragma unroll
    for (int r = 0; r < 2; ++r)
#pragma unroll
        for (int c = 0; c < 4; ++c) { Sr[r][c] = zero; Si[r][c] = zero; }

#pragma unroll
    for (int kq0 = 0; kq0 < 256; kq0 += 32) {
        h8 ahr[2], alr[2], ahi[2], ali[2];
#pragma unroll
        for (int rr = 0; rr < 2; ++rr) {
            const int ko = (rr ? ko1 : ko0) + kq0;
            ahr[rr] = *(const h8*)(Kp0 + ko); alr[rr] = *(const h8*)(Kp1 + ko);
            ahi[rr] = *(const h8*)(Kp2 + ko); ali[rr] = *(const h8*)(Kp3 + ko);
        }
#pragma unroll
        for (int cc = 0; cc < 4; ++cc) {
            h8 bhr = *(const h8*)(Qp0 + qo[cc] + kq0);
            h8 blr = *(const h8*)(Qp1 + qo[cc] + kq0);
            h8 bhi = *(const h8*)(Qp2 + qo[cc] + kq0);
            h8 bli = *(const h8*)(Qp3 + qo[cc] + kq0);
            h8 nbhi = -bhi, nbli = -bli;   // transient; (-a)*b == a*(-b)
            __builtin_amdgcn_s_setprio(1);   // T5: favor MFMA-burst wave
#pragma unroll
            for (int rr = 0; rr < 2; ++rr) {
                Sr[rr][cc] = MFMA16(ahr[rr], bhr, Sr[rr][cc]);
                Sr[rr][cc] = MFMA16(ahr[rr], blr, Sr[rr][cc]);
                Sr[rr][cc] = MFMA16(alr[rr], bhr, Sr[rr][cc]);
                Sr[rr][cc] = MFMA16(ahi[rr], nbhi, Sr[rr][cc]);
                Sr[rr][cc] = MFMA16(ahi[rr], nbli, Sr[rr][cc]);
                Sr[rr][cc] = MFMA16(ali[rr], nbhi, Sr[rr][cc]);
                Si[rr][cc] = MFMA16(ahr[rr], bhi, Si[rr][cc]);
                Si[rr][cc] = MFMA16(ahr[rr], bli, Si[rr][cc]);
                Si[rr][cc] = MFMA16(alr[rr], bhi, Si[rr][cc]);
                Si[rr][cc] = MFMA16(ahi[rr], bhr, Si[rr][cc]);
                Si[rr][cc] = MFMA16(ahi[rr], blr, Si[rr][cc]);
                Si[rr][cc] = MFMA16(ali[rr], bhr, Si[rr][cc]);
            }
            __builtin_amdgcn_s_setprio(0);
        }
    }
    // epilogue: + pos, |.|/8, transpose via LDS, write S[z][j][i]; two J-halves
#pragma unroll
    for (int jh = 0; jh < 2; ++jh) {
        if (jh) __syncthreads();
        float wc2[2][4], ws2[2][4];
#pragma unroll
        for (int c = 0; c < 2; ++c) {
            int j = J0 + jh * 64 + wx * 32 + c * 16 + l16;
#pragma unroll
            for (int k = 0; k < 4; ++k) { wc2[c][k] = wtc[k * 1024 + j]; ws2[c][k] = wts[k * 1024 + j]; }
        }
#pragma unroll
        for (int rr = 0; rr < 2; ++rr)
#pragma unroll
            for (int reg = 0; reg < 4; ++reg) {
                int i = I0 + wy * 32 + rr * 16 + quad * 4 + reg;
                float g_r[4], g_i[4];
#pragma unroll
                for (int k = 0; k < 4; ++k) {
                    g_r[k] = ggr[(size_t)(z * 4 + k) * 1024 + i];
                    g_i[k] = ggi[(size_t)(z * 4 + k) * 1024 + i];
                }
#pragma unroll
                for (int c = 0; c < 2; ++c) {
                    int cc = jh * 2 + c;
                    float pr = 0.f, pi = 0.f;
#pragma unroll
                    for (int k = 0; k < 4; ++k) {
                        pr += g_r[k] * wc2[c][k] + g_i[k] * ws2[c][k];
                        pi += g_i[k] * wc2[c][k] - g_r[k] * ws2[c][k];
                    }
                    float ar = Sr[rr][cc][reg] + pr, ai = Si[rr][cc][reg] + pi;
                    int jl = wx * 32 + c * 16 + l16, il = wy * 32 + rr * 16 + quad * 4 + reg;
                    T[jl][il] = sqrtf(ar * ar + ai * ai) * 0.125f;
                }
            }
        __syncthreads();
        {
            int j2 = t >> 2, ch = (t & 3) * 16;
            float4* Tp = (float4*)&T[j2][ch];
            float4* dst = (float4*)(S + ((size_t)z * 1024 + J0 + jh * 64 + j2) * 1024 + I0 + ch);
#pragma unroll
            for (int w = 0; w < 4; ++w) dst[w] = Tp[w];
        }
    }
}

// ---------------- k_colred: row max, expsum, fp16 Pg plane -----------------
__global__ __launch_bounds__(256) void k_colred(
    const float* __restrict__ S, float* __restrict__ cmax, float* __restrict__ csum,
    h16* __restrict__ Pg)
{
    __shared__ float sm[256];
    const int t = threadIdx.x;
    size_t row = blockIdx.x;
    float4 v = ((const float4*)(S + row * 1024))[t];
    float m = fmaxf(fmaxf(v.x, v.y), fmaxf(v.z, v.w));
    sm[t] = m; __syncthreads();
    for (int s = 128; s > 0; s >>= 1) { if (t < s) sm[t] = fmaxf(sm[t], sm[t + s]); __syncthreads(); }
    float M = sm[0]; __syncthreads();
    float e0 = __expf(v.x - M), e1 = __expf(v.y - M), e2 = __expf(v.z - M), e3 = __expf(v.w - M);
    sm[t] = e0 + e1 + e2 + e3; __syncthreads();
    for (int s = 128; s > 0; s >>= 1) { if (t < s) sm[t] += sm[t + s]; __syncthreads(); }
    h4 p; p[0] = (h16)e0; p[1] = (h16)e1; p[2] = (h16)e2; p[3] = (h16)e3;
    *(h4*)(Pg + row * 2048 + t * 4) = p;
    if (t == 0) { cmax[row] = M; csum[row] = sm[0]; }
}

// ---------------- k_qkv_v: V = emb2 @ x (plain fp16 MFMA) ------------------
__global__ __launch_bounds__(256) void k_qkv_v(
    const h16* __restrict__ e2hr, const h16* __restrict__ e2hi,
    const h16* __restrict__ x2hr, const h16* __restrict__ x2hi,
    h16* __restrict__ vr, h16* __restrict__ vi)
{
    __shared__ __align__(16) h16 smem[15360];
    h16* A2[2]; h16* B2[2];
#pragma unroll
    for (int p = 0; p < 2; ++p) { A2[p] = smem + p * 5120; B2[p] = smem + 10240 + p * 2560; }
    const int t = threadIdx.x, bk = blockIdx.z, kk = bk & 3;
    const int N0 = blockIdx.x * 64, D0 = blockIdx.y * 128;
    const int wave = t >> 6, lane = t & 63, quad = lane >> 4, l16 = lane & 15;
    const int wy = wave >> 1, wx = wave & 1;
    const h16* APl[2] = { e2hr + (size_t)kk * 262144, e2hi + (size_t)kk * 262144 };
    const h16* BPl[2] = { x2hr + (size_t)bk * 524288, x2hi + (size_t)bk * 524288 };

    f4 zero = {0.f, 0.f, 0.f, 0.f};
    f4 Rc[4][2], Ic[4][2];
#pragma unroll
    for (int r = 0; r < 4; ++r)
#pragma unroll
        for (int c = 0; c < 2; ++c) { Rc[r][c] = zero; Ic[r][c] = zero; }

    for (int c0 = 0; c0 < Cd; c0 += 32) {
#pragma unroll
        for (int s = 0; s < 3; ++s) {
            int seg = t + 256 * s;
            const h16* src; h16* dst;
            if (seg < 512) {
                int p = seg >> 8, rem = seg & 255, row = rem >> 1, ch = rem & 1;
                src = APl[p] + (size_t)(D0 + row) * 512 + c0 + ch * 16;
                dst = A2[p] + row * 40 + ch * 16;
            } else {
                int s2 = seg - 512, p = s2 >> 7, rem = s2 & 127, row = rem >> 1, ch = rem & 1;
                src = BPl[p] + (size_t)(N0 + row) * 512 + c0 + ch * 16;
                dst = B2[p] + row * 40 + ch * 16;
            }
            const uint4* s4 = (const uint4*)src; uint4 v0 = s4[0], v1 = s4[1];
            uint4* d4 = (uint4*)dst; d4[0] = v0; d4[1] = v1;
        }
        __syncthreads();
        h8 bhr[2], bhi[2];
#pragma unroll
        for (int cc = 0; cc < 2; ++cc) {
            int o = (wx * 32 + cc * 16 + l16) * 40 + quad * 8;
            bhr[cc] = *(const h8*)(B2[0] + o); bhi[cc] = *(const h8*)(B2[1] + o);
        }
#pragma unroll
        for (int rr = 0; rr < 4; ++rr) {
            int o = (wy * 64 + rr * 16 + l16) * 40 + quad * 8;
            h8 ahr = *(const h8*)(A2[0] + o), ahi = *(const h8*)(A2[1] + o);
            h8 nhi = -ahi;
#pragma unroll
            for (int cc = 0; cc < 2; ++cc) {
                Rc[rr][cc] = MFMA16(ahr, bhr[cc], Rc[rr][cc]);
                Rc[rr][cc] = MFMA16(nhi, bhi[cc], Rc[rr][cc]);
                Ic[rr][cc] = MFMA16(ahr, bhi[cc], Ic[rr][cc]);
                Ic[rr][cc] = MFMA16(ahi, bhr[cc], Ic[rr][cc]);
            }
        }
        __syncthreads();
    }
#pragma unroll
    for (int rr = 0; rr < 4; ++rr)
#pragma unroll
        for (int cc = 0; cc < 2; ++cc)
#pragma unroll
            for (int reg = 0; reg < 4; ++reg) {
                int dl = D0 + wy * 64 + rr * 16 + quad * 4 + reg;
                int nl = N0 + wx * 32 + cc * 16 + l16;
                size_t o = (size_t)bk * 524288 + (size_t)dl * 1024 + nl;
                vr[o] = (h16)Rc[rr][cc][reg];
                vi[o] = (h16)Ic[rr][cc][reg];
            }
}

// ---------------- k_ctx: ctx = V @ P, fp16, transposed out -----------------
// R14 structure: staged LDS; P staged from fp16 Pg plane.
__global__ __launch_bounds__(256) void k_ctx(
    const h16* __restrict__ vr, const h16* __restrict__ vi,
    const h16* __restrict__ Pg, const float* __restrict__ csum,
    h16* __restrict__ ctr, h16* __restrict__ cti)
{
    __shared__ __align__(16) h16 Vsr[2560], Vsi[2560], Ps[2560];
    __shared__ __align__(16) h16 T2[4608];  // 64 x 72
    const int t = threadIdx.x, z = blockIdx.z, kk = blockIdx.y, M0 = blockIdx.x * 64;
    const int b = z >> 3, h = z & 7;
    const int wave = t >> 6, lane = t & 63, quad = lane >> 4, l16 = lane & 15;
    const int wy = wave >> 1, wx = wave & 1;
    const size_t vbase = (size_t)(b * 4 + kk) * 524288 + (size_t)(h * 64) * 1024;
    const size_t pbase = (size_t)(z * 1024 + M0);

    f4 zero = {0.f, 0.f, 0.f, 0.f};
    f4 accR[2][2], accI[2][2];
#pragma unroll
    for (int r = 0; r < 2; ++r)
#pragma unroll
        for (int c = 0; c < 2; ++c) { accR[r][c] = zero; accI[r][c] = zero; }

    for (int i0 = 0; i0 < 1024; i0 += 32) {
        if (t < 128) {
            int comp = t >> 6, q = t & 63;
            const h16* src = (comp ? vi : vr) + vbase + (size_t)q * 1024 + i0;
            h16* dst = (comp ? Vsi : Vsr) + q * 40;
            const uint4* s4 = (const uint4*)src;
#pragma unroll
            for (int w = 0; w < 4; ++w) ((uint4*)dst)[w] = s4[w];
        } else {
            int tt = t - 128, m = tt >> 1, ch = tt & 1;
            const h16* sp = Pg + (pbase + m) * 2048 + i0 + ch * 16;
            h16* dst = Ps + m * 40 + ch * 16;
            ((uint4*)dst)[0] = ((const uint4*)sp)[0];
            ((uint4*)dst)[1] = ((const uint4*)sp)[1];
        }
        __syncthreads();
        h8 bp[2];
#pragma unroll
        for (int cc = 0; cc < 2; ++cc)
            bp[cc] = *(const h8*)(Ps + (wx * 32 + cc * 16 + l16) * 40 + quad * 8);
#pragma unroll
        for (int rr = 0; rr < 2; ++rr) {
            int o = (wy * 32 + rr * 16 + l16) * 40 + quad * 8;
            h8 avr = *(const h8*)(Vsr + o), avi = *(const h8*)(Vsi + o);
#pragma unroll
            for (int cc = 0; cc < 2; ++cc) {
                accR[rr][cc] = MFMA16(avr, bp[cc], accR[rr][cc]);
                accI[rr][cc] = MFMA16(avi, bp[cc], accI[rr][cc]);
            }
        }
        __syncthreads();
    }
    for (int round = 0; round < 2; ++round) {
#pragma unroll
        for (int rr = 0; rr < 2; ++rr)
#pragma unroll
            for (int cc = 0; cc < 2; ++cc) {
                int ml = wx * 32 + cc * 16 + l16;
                float inv = 1.0f / csum[(size_t)z * 1024 + M0 + ml];
#pragma unroll
                for (int reg = 0; reg < 4; ++reg) {
                    int ql = wy * 32 + rr * 16 + quad * 4 + reg;
                    float v = (round ? accI[rr][cc][reg] : accR[rr][cc][reg]) * inv;
                    T2[ml * 72 + ql] = (h16)v;
                }
            }
        __syncthreads();
        {
            int m = t >> 2, ch = (t & 3) * 16;
            h8 v0 = *(const h8*)(T2 + m * 72 + ch), v1 = *(const h8*)(T2 + m * 72 + ch + 8);
            h16* dst = (round ? cti : ctr) + (size_t)(b * 4 + kk) * 524288 + (size_t)(M0 + m) * 512 + h * 64 + ch;
            *(h8*)dst = v0; *(h8*)(dst + 8) = v1;
        }
        __syncthreads();
    }
}

// ---------------- k_out: res = Re(out @ ctx), MFMA fp16 --------------------
__global__ __launch_bounds__(256) void k_out(
    const float* __restrict__ outr, const float* __restrict__ outi,
    const h16* __restrict__ ctr, const h16* __restrict__ cti,
    float* __restrict__ res)
{
    __shared__ __align__(16) h16 smem[10240];
    h16* Asr; h16* Asi; h16* Bsr; h16* Bsi;
    Asr = smem; Asi = smem + 2560; Bsr = smem + 5120; Bsi = smem + 7680;
    const int t = threadIdx.x, bk = blockIdx.z, kk = bk & 3;
    const int N0 = blockIdx.x * 64, D0 = blockIdx.y * 64;
    const int wave = t >> 6, lane = t & 63, quad = lane >> 4, l16 = lane & 15;
    const int wy = wave >> 1, wx = wave & 1;

    f4 zero = {0.f, 0.f, 0.f, 0.f};
    f4 P1[2][2], P2[2][2];
#pragma unroll
    for (int r = 0; r < 2; ++r)
#pragma unroll
        for (int c = 0; c < 2; ++c) { P1[r][c] = zero; P2[r][c] = zero; }

    for (int c0 = 0; c0 < Cd; c0 += 32) {
        {   // stage A: out fp32 -> fp16
            int comp = t >> 7, rem = t & 127, row = rem >> 1, ch = rem & 1;
            const float4* sp = (const float4*)((comp ? outi : outr) + (size_t)kk * 262144 + (size_t)(D0 + row) * 512 + c0 + ch * 16);
            h8 h0v, h1v;
#pragma unroll
            for (int w = 0; w < 4; ++w) {
                float4 v = sp[w];
                h16 a = (h16)v.x, b2 = (h16)v.y, c = (h16)v.z, d = (h16)v.w;
                if (w < 2) { h0v[w*4] = a; h0v[w*4+1] = b2; h0v[w*4+2] = c; h0v[w*4+3] = d; }
                else { h1v[(w-2)*4] = a; h1v[(w-2)*4+1] = b2; h1v[(w-2)*4+2] = c; h1v[(w-2)*4+3] = d; }
            }
            h16* dst = (comp ? Asi : Asr) + row * 40 + ch * 16;
            *(h8*)dst = h0v; *(h8*)(dst + 8) = h1v;
        }
        {   // stage B: ctx_t fp16 copy
            int comp = t >> 7, rem = t & 127, row = rem >> 1, ch = rem & 1;
            const h16* src = (comp ? cti : ctr) + (size_t)bk * 524288 + (size_t)(N0 + row) * 512 + c0 + ch * 16;
            h16* dst = (comp ? Bsi : Bsr) + row * 40 + ch * 16;
            const uint4* s4 = (const uint4*)src; uint4 v0 = s4[0], v1 = s4[1];
            uint4* d4 = (uint4*)dst; d4[0] = v0; d4[1] = v1;
        }
        __syncthreads();
        h8 br[2], bi[2];
#pragma unroll
        for (int cc = 0; cc < 2; ++cc) {
            int o = (wx * 32 + cc * 16 + l16) * 40 + quad * 8;
            br[cc] = *(const h8*)(Bsr + o); bi[cc] = *(const h8*)(Bsi + o);
        }
#pragma unroll
        for (int rr = 0; rr < 2; ++rr) {
            int o = (wy * 32 + rr * 16 + l16) * 40 + quad * 8;
            h8 ar = *(const h8*)(Asr + o), ai = *(const h8*)(Asi + o);
#pragma unroll
            for (int cc = 0; cc < 2; ++cc) {
                P1[rr][cc] = MFMA16(ar, br[cc], P1[rr][cc]);
                P2[rr][cc] = MFMA16(ai, bi[cc], P2[rr][cc]);
            }
        }
        __syncthreads();
    }
#pragma unroll
    for (int rr = 0; rr < 2; ++rr)
#pragma unroll
        for (int cc = 0; cc < 2; ++cc)
#pragma unroll
            for (int reg = 0; reg < 4; ++reg) {
                int dl = D0 + wy * 32 + rr * 16 + quad * 4 + reg;
                int nl = N0 + wx * 32 + cc * 16 + l16;
                res[(size_t)bk * 524288 + (size_t)dl * 1024 + nl] = P1[rr][cc][reg] - P2[rr][cc][reg];
            }
}

extern "C" void kernel_launch(void* const* d_in, const int* in_sizes, int n_in,
                              void* d_out, int out_size, void* d_ws, size_t ws_size,
                              hipStream_t stream)
{
    const float* xr    = (const float*)d_in[0];
    const float* xi    = (const float*)d_in[1];
    const float* embr  = (const float*)d_in[2];
    const float* embi  = (const float*)d_in[3];
    const float* encr  = (const float*)d_in[4];
    const float* enci  = (const float*)d_in[5];
    const float* softr = (const float*)d_in[6];
    const float* softi = (const float*)d_in[7];
    const float* outr  = (const float*)d_in[8];
    const float* outi  = (const float*)d_in[9];
    float* res = (float*)d_out;
    char* ws   = (char*)d_ws;
    if (ws_size < (size_t)268435456) return;

    h16* qhr = (h16*)(ws + QHR); h16* qlr = (h16*)(ws + QLR);
    h16* qhi = (h16*)(ws + QHI); h16* qli = (h16*)(ws + QLI);
    h16* khr = (h16*)(ws + KHR); h16* klr = (h16*)(ws + KLR);
    h16* khi = (h16*)(ws + KHI); h16* kli = (h16*)(ws + KLI);
    float* S  = (float*)(ws + SOFF);
    h16* Pg   = (h16*)(ws + SOFF);   // fp16 P plane aliases S rows (row-aligned)
    h16* xthr = (h16*)(ws + XTHR); h16* xtlr = (h16*)(ws + XTLR);
    h16* xthi = (h16*)(ws + XTHI); h16* xtli = (h16*)(ws + XTLI);
    h16* ehr = (h16*)(ws + EHR); h16* elr = (h16*)(ws + ELR);
    h16* ehi = (h16*)(ws + EHI); h16* eli = (h16*)(ws + ELI);
    h16* x2hr = (h16*)(ws + X2HR); h16* x2hi = (h16*)(ws + X2HI);
    h16* e2hr = (h16*)(ws + E2HR); h16* e2hi = (h16*)(ws + E2HI);
    h16* vr = (h16*)(ws + VRO); h16* vi = (h16*)(ws + VIO);
    h16* ctr = (h16*)(ws + CTR); h16* cti = (h16*)(ws + CTI);
    float* sc = (float*)d_out;  // scratch in d_out, overwritten by k_out last
    float* ggr = sc + GG_R; float* ggi = sc + GG_I;
    float* wtc = sc + WT_C; float* wts = sc + WT_S;
    float* cmax = sc + CMAX; float* csum = sc + CSUM;

    k_prep_x<0><<<dim3(16, 8, 16), 256, 0, stream>>>(xr, xi, xthr, xtlr, xthi, xtli);
    k_prep_emb<0><<<dim3(2048), 256, 0, stream>>>(embr, embi, 0, ehr, elr, ehi, eli);
    k_wtab<<<dim3(16), 256, 0, stream>>>(wtc, wts);
    k_qkv01<<<dim3(16, 4, 32), 256, 0, stream>>>(ehr, elr, ehi, eli, xthr, xtlr, xthi, xtli,
                                                 qhr, qlr, qhi, qli, khr, klr, khi, kli, softr, softi);
    k_gg<<<dim3(4, 128), 256, 0, stream>>>(qhr, qlr, qhi, qli, encr, enci, softr, softi, ggr, ggi);
    k_scores<<<dim3(8, 16, 32), 256, 0, stream>>>(khr, klr, khi, kli, qhr, qlr, qhi, qli,
                                                  ggr, ggi, wtc, wts, S);
    k_colred<<<dim3(32768), 256, 0, stream>>>(S, cmax, csum, Pg);
    k_prep_x<1><<<dim3(16, 8, 16), 256, 0, stream>>>(xr, xi, x2hr, x2hr, x2hi, x2hi);
    k_prep_emb<1><<<dim3(1024), 256, 0, stream>>>(embr, embi, 2097152, e2hr, e2hr, e2hi, e2hi);
    k_qkv_v<<<dim3(16, 4, 16), 256, 0, stream>>>(e2hr, e2hi, x2hr, x2hi, vr, vi);
    k_ctx<<<dim3(16, 4, 32), 256, 0, stream>>>(vr, vi, Pg, csum, ctr, cti);
    k_out<<<dim3(16, 8, 16), 256, 0, stream>>>(outr, outi, ctr, cti, res);
}

// Round 16
// 1143.717 us; speedup vs baseline: 1.0192x; 1.0036x over previous
//
#include <hip/hip_runtime.h>
#include <cstdio>
#include <cmath>

// SE2 multi self-attention forward — R21: R20 champion (1146.7/1150.3/1147.9
// verified) + ONE bounded-risk change: k_colred reductions via wave-level
// __shfl_xor butterflies (16 barriers -> 2 per block; 32768 blocks). Max is
// exact under reorder; sum reassociation within exercised tolerance.
// Tripwire: k_scores must hold 489+-6 / VGPR 152 / FETCH 299.5MB (R18/R19
// showed sibling-code perturbation = same counters, +8% time -> revert).
// Config: k_scores 64x128 direct-global + T5 setprio; qkv01/qkv_v/ctx/out
// staged-LDS 32-wide; colred writes fp16 Pg plane; 2-family accumulators.
// MFMA layouts (gfx950, verified): A[m=lane&15][k=(lane>>4)*8+j],
// B[k=(lane>>4)*8+j][n=lane&15], C/D col=lane&15,row=(lane>>4)*4+reg.

typedef _Float16 h16;
typedef h16 h8 __attribute__((ext_vector_type(8)));
typedef h16 h4 __attribute__((ext_vector_type(4)));
typedef float f4 __attribute__((ext_vector_type(4)));

#define MFMA16(A, B, C) __builtin_amdgcn_mfma_f32_16x16x32_f16(A, B, C, 0, 0, 0)

constexpr int Bb = 4, Mm = 4, Cd = 512, Np = 1024, Nh = 8, Qd = 64;
constexpr float W0 = (float)(2.0 * 3.14159265358979323846 / 1024.0);

// workspace offsets (bytes)
constexpr size_t PL   = 16777216;        // one fp16 plane: 16*512*1024 halves
constexpr size_t QHR = 0, QLR = PL, QHI = 2*PL, QLI = 3*PL;
constexpr size_t KHR = 4*PL, KLR = 5*PL, KHI = 6*PL, KLI = 7*PL;
constexpr size_t SOFF = 8*PL;            // S fp32: 134217728 B (Pg aliases rows)
constexpr size_t XTHR = SOFF, XTLR = SOFF+PL, XTHI = SOFF+2*PL, XTLI = SOFF+3*PL;
constexpr size_t EHR = SOFF+4*PL, ELR = EHR+4194304, EHI = EHR+8388608, ELI = EHR+12582912;
constexpr size_t X2HR = KHR, X2HI = KHR+PL;
constexpr size_t E2HR = KHR+2*PL, E2HI = E2HR+2097152;
constexpr size_t VRO = 0, VIO = PL, CTR = 2*PL, CTI = 3*PL;
// d_out scratch offsets (floats)
constexpr size_t GG_R = 0, GG_I = 131072, WT_C = 262144, WT_S = 266240,
                 CMAX = 270336, CSUM = 303104;

__device__ __forceinline__ unsigned short h2u(h16 h) { return __builtin_bit_cast(unsigned short, h); }
__device__ __forceinline__ void fsplit(float v, h16& h, h16& l) {
    h = (h16)v; l = (h16)(v - (float)h);
}

// ---------------- prep: x -> transposed fp16 planes [bk][n][c] -------------
template <int HIONLY>
__global__ __launch_bounds__(256) void k_prep_x(
    const float* __restrict__ xr, const float* __restrict__ xi,
    h16* __restrict__ phr, h16* __restrict__ plr,
    h16* __restrict__ phi, h16* __restrict__ pli)
{
    __shared__ float T[64][68];
    const int bk = blockIdx.z, N0 = blockIdx.x * 64, C0 = blockIdx.y * 64;
    const int t = threadIdx.x;
    for (int comp = 0; comp < 2; ++comp) {
        const float* src = (comp ? xi : xr) + (size_t)bk * Cd * Np;
        {   // stage x[c][n] tile
            int cc = t >> 2, ch = (t & 3) * 16;
            const float4* s4 = (const float4*)(src + (size_t)(C0 + cc) * Np + N0 + ch);
            float4 a = s4[0], b = s4[1], c = s4[2], d = s4[3];
            float4* dst = (float4*)&T[cc][ch];
            dst[0] = a; dst[1] = b; dst[2] = c; dst[3] = d;
        }
        __syncthreads();
        {   // drain transposed [n][c], split to fp16 hi/lo
            int n = t >> 2, ch = (t & 3) * 16;
            h8 hv0, hv1, lv0, lv1;
#pragma unroll
            for (int jj = 0; jj < 16; ++jj) {
                h16 h, l; fsplit(T[ch + jj][n], h, l);
                if (jj < 8) { hv0[jj] = h; lv0[jj] = l; }
                else        { hv1[jj - 8] = h; lv1[jj - 8] = l; }
            }
            size_t off = (size_t)bk * Np * Cd + (size_t)(N0 + n) * Cd + C0 + ch;
            h16* dh = (comp ? phi : phr) + off;
            *(h8*)dh = hv0; *(h8*)(dh + 8) = hv1;
            if (!HIONLY) {
                h16* dl = (comp ? pli : plr) + off;
                *(h8*)dl = lv0; *(h8*)(dl + 8) = lv1;
            }
        }
        __syncthreads();
    }
}

// ---------------- prep: emb -> fp16 planes (elementwise) -------------------
template <int HIONLY>
__global__ __launch_bounds__(256) void k_prep_emb(
    const float* __restrict__ er, const float* __restrict__ ei, size_t srcbase,
    h16* __restrict__ phr, h16* __restrict__ plr,
    h16* __restrict__ phi, h16* __restrict__ pli)
{
    size_t idx = ((size_t)blockIdx.x * 256 + threadIdx.x) * 4;
    float4 vr = *(const float4*)(er + srcbase + idx);
    float4 vi = *(const float4*)(ei + srcbase + idx);
    h4 hr, lr, hi, li;
    float ar[4] = {vr.x, vr.y, vr.z, vr.w}, ai[4] = {vi.x, vi.y, vi.z, vi.w};
#pragma unroll
    for (int j = 0; j < 4; ++j) {
        h16 h, l; fsplit(ar[j], h, l); hr[j] = h; lr[j] = l;
        fsplit(ai[j], h, l); hi[j] = h; li[j] = l;
    }
    *(h4*)(phr + idx) = hr; *(h4*)(phi + idx) = hi;
    if (!HIONLY) { *(h4*)(plr + idx) = lr; *(h4*)(pli + idx) = li; }
}

// ---------------- wtab: cos/sin(W0*k*j) ------------------------------------
__global__ __launch_bounds__(256) void k_wtab(float* __restrict__ wtc, float* __restrict__ wts)
{
    int idx = blockIdx.x * 256 + threadIdx.x;  // 4096
    int kk = idx >> 10, j = idx & 1023;
    float sn, cs; sincosf(W0 * (float)(kk * j), &sn, &cs);
    wtc[idx] = cs; wts[idx] = sn;
}

// ---------------- k_qkv01: E = emb @ x, split-fp16 MFMA, Q/K out -----------
// R8 staging structure + 2-family accumulators (R15 showed direct regresses).
__global__ __launch_bounds__(256) void k_qkv01(
    const h16* __restrict__ ehr, const h16* __restrict__ elr,
    const h16* __restrict__ ehi, const h16* __restrict__ eli,
    const h16* __restrict__ xthr, const h16* __restrict__ xtlr,
    const h16* __restrict__ xthi, const h16* __restrict__ xtli,
    h16* __restrict__ qhr, h16* __restrict__ qlr, h16* __restrict__ qhi, h16* __restrict__ qli,
    h16* __restrict__ khr, h16* __restrict__ klr, h16* __restrict__ khi, h16* __restrict__ kli,
    const float* __restrict__ softr, const float* __restrict__ softi)
{
    __shared__ __align__(16) char smem[61440];
    h16* As[4]; h16* Bs[4];
#pragma unroll
    for (int p = 0; p < 4; ++p) { As[p] = (h16*)smem + p * 5120; Bs[p] = (h16*)smem + 20480 + p * 2560; }
    uint* T = (uint*)smem;  // 64 x 132 overlay (epilogue)

    const int t = threadIdx.x;
    const int z = blockIdx.z, e = z >> 4, bk = z & 15, b = bk >> 2, kk = bk & 3;
    const int N0 = blockIdx.x * 64, D0 = blockIdx.y * 128;
    const int wave = t >> 6, lane = t & 63, quad = lane >> 4, l16 = lane & 15;
    const int wy = wave >> 1, wx = wave & 1;

    const h16* APl[4] = { ehr + (size_t)(e * 4 + kk) * 262144, elr + (size_t)(e * 4 + kk) * 262144,
                          ehi + (size_t)(e * 4 + kk) * 262144, eli + (size_t)(e * 4 + kk) * 262144 };
    const h16* BPl[4] = { xthr + (size_t)bk * 524288, xtlr + (size_t)bk * 524288,
                          xthi + (size_t)bk * 524288, xtli + (size_t)bk * 524288 };

    f4 zero = {0.f, 0.f, 0.f, 0.f};
    f4 Er[4][2], Ei[4][2];
#pragma unroll
    for (int r = 0; r < 4; ++r)
#pragma unroll
        for (int c = 0; c < 2; ++c) { Er[r][c] = zero; Ei[r][c] = zero; }

    for (int c0 = 0; c0 < Cd; c0 += 32) {
#pragma unroll
        for (int s = 0; s < 6; ++s) {
            int seg = t + 256 * s;
            const h16* src; h16* dst;
            if (seg < 1024) {
                int p = seg >> 8, rem = seg & 255, row = rem >> 1, ch = rem & 1;
                src = APl[p] + (size_t)(D0 + row) * 512 + c0 + ch * 16;
                dst = As[p] + row * 40 + ch * 16;
            } else {
                int s2 = seg - 1024, p = s2 >> 7, rem = s2 & 127, row = rem >> 1, ch = rem & 1;
                src = BPl[p] + (size_t)(N0 + row) * 512 + c0 + ch * 16;
                dst = Bs[p] + row * 40 + ch * 16;
            }
            const uint4* s4 = (const uint4*)src; uint4 v0 = s4[0], v1 = s4[1];
            uint4* d4 = (uint4*)dst; d4[0] = v0; d4[1] = v1;
        }
        __syncthreads();
        h8 bhr[2], blr[2], bhi[2], bli[2];
#pragma unroll
        for (int cc = 0; cc < 2; ++cc) {
            int o = (wx * 32 + cc * 16 + l16) * 40 + quad * 8;
            bhr[cc] = *(const h8*)(Bs[0] + o); blr[cc] = *(const h8*)(Bs[1] + o);
            bhi[cc] = *(const h8*)(Bs[2] + o); bli[cc] = *(const h8*)(Bs[3] + o);
        }
#pragma unroll
        for (int rr = 0; rr < 4; ++rr) {
            int o = (wy * 64 + rr * 16 + l16) * 40 + quad * 8;
            h8 ahr = *(const h8*)(As[0] + o), alr = *(const h8*)(As[1] + o);
            h8 ahi = *(const h8*)(As[2] + o), ali = *(const h8*)(As[3] + o);
            h8 nhi = -ahi, nli = -ali;
#pragma unroll
            for (int cc = 0; cc < 2; ++cc) {
                Er[rr][cc] = MFMA16(ahr, bhr[cc], Er[rr][cc]);
                Er[rr][cc] = MFMA16(ahr, blr[cc], Er[rr][cc]);
                Er[rr][cc] = MFMA16(alr, bhr[cc], Er[rr][cc]);
                Er[rr][cc] = MFMA16(nhi, bhi[cc], Er[rr][cc]);
                Er[rr][cc] = MFMA16(nhi, bli[cc], Er[rr][cc]);
                Er[rr][cc] = MFMA16(nli, bhi[cc], Er[rr][cc]);
                Ei[rr][cc] = MFMA16(ahr, bhi[cc], Ei[rr][cc]);
                Ei[rr][cc] = MFMA16(ahr, bli[cc], Ei[rr][cc]);
                Ei[rr][cc] = MFMA16(alr, bhi[cc], Ei[rr][cc]);
                Ei[rr][cc] = MFMA16(ahi, bhr[cc], Ei[rr][cc]);
                Ei[rr][cc] = MFMA16(ahi, blr[cc], Ei[rr][cc]);
                Ei[rr][cc] = MFMA16(ali, bhr[cc], Ei[rr][cc]);
            }
        }
        __syncthreads();
    }
    // conj / soft-fold
    f4 ER[4][2], EI[4][2];
#pragma unroll
    for (int rr = 0; rr < 4; ++rr) {
        int h = (D0 + wy * 64 + rr * 16) >> 6;
        float sr = 0.f, si = 0.f;
        if (e == 1) { sr = softr[kk * 8 + h]; si = softi[kk * 8 + h]; }
#pragma unroll
        for (int cc = 0; cc < 2; ++cc) {
            f4 er = Er[rr][cc];
            f4 ei = Ei[rr][cc];
            if (e == 0) { ei = -ei; }                  // Q = conj(E0)
            else { f4 t1 = sr * er - si * ei; ei = sr * ei + si * er; er = t1; }  // K' = soft*K
            ER[rr][cc] = er; EI[rr][cc] = ei;
        }
    }
    const int h0 = D0 >> 6;
    for (int round = 0; round < 2; ++round) {
#pragma unroll
        for (int rr = 0; rr < 4; ++rr)
#pragma unroll
            for (int cc = 0; cc < 2; ++cc)
#pragma unroll
                for (int reg = 0; reg < 4; ++reg) {
                    int dl = wy * 64 + rr * 16 + quad * 4 + reg;
                    int nl = wx * 32 + cc * 16 + l16;
                    float v = round ? EI[rr][cc][reg] : ER[rr][cc][reg];
                    h16 hh, ll; fsplit(v, hh, ll);
                    T[nl * 132 + dl] = ((uint)h2u(hh) << 16) | (uint)h2u(ll);
                }
        __syncthreads();
        {
            int seg = t >> 1, sub = t & 1, n = seg & 63, hh2 = seg >> 6;
            int off = hh2 * 64 + sub * 32;
            uint tmp[32];
            uint4* Tp = (uint4*)&T[n * 132 + off];
#pragma unroll
            for (int w = 0; w < 8; ++w) ((uint4*)tmp)[w] = Tp[w];
            uint hiu[16], lou[16];
#pragma unroll
            for (int w = 0; w < 16; ++w) {
                uint a = tmp[2 * w], b2 = tmp[2 * w + 1];
                hiu[w] = (a >> 16) | (b2 & 0xffff0000u);
                lou[w] = (a & 0xffffu) | (b2 << 16);
            }
            int hg = h0 + hh2;
            size_t dsto = ((size_t)((b * 8 + hg) * 1024 + N0 + n)) * 256 + kk * 64 + sub * 32;
            h16* dh; h16* dl;
            if (round == 0) { dh = (e ? khr : qhr) + dsto; dl = (e ? klr : qlr) + dsto; }
            else            { dh = (e ? khi : qhi) + dsto; dl = (e ? kli : qli) + dsto; }
#pragma unroll
            for (int w = 0; w < 4; ++w) ((uint4*)dh)[w] = ((uint4*)hiu)[w];
#pragma unroll
            for (int w = 0; w < 4; ++w) ((uint4*)dl)[w] = ((uint4*)lou)[w];
        }
        __syncthreads();
    }
}

// ---------------- k_gg: vectorized h8 loads --------------------------------
__global__ __launch_bounds__(256) void k_gg(
    const h16* __restrict__ qhr, const h16* __restrict__ qlr,
    const h16* __restrict__ qhi, const h16* __restrict__ qli,
    const float* __restrict__ encr, const float* __restrict__ enci,
    const float* __restrict__ softr, const float* __restrict__ softi,
    float* __restrict__ ggr, float* __restrict__ ggi)
{
    const int i = blockIdx.x * 256 + threadIdx.x;
    const int z2 = blockIdx.y, kk = z2 & 3, z = z2 >> 2, h = z & 7;
    size_t base = ((size_t)z * 1024 + i) * 256 + kk * 64;
    float gr = 0.f, gi = 0.f;
    const int eb = (kk * 8 + h) * 64;
#pragma unroll
    for (int q8 = 0; q8 < 8; ++q8) {
        h8 vhr = *(const h8*)(qhr + base + q8 * 8);
        h8 vlr = *(const h8*)(qlr + base + q8 * 8);
        h8 vhi = *(const h8*)(qhi + base + q8 * 8);
        h8 vli = *(const h8*)(qli + base + q8 * 8);
#pragma unroll
        for (int j = 0; j < 8; ++j) {
            float qr = (float)vhr[j] + (float)vlr[j];
            float qi = (float)vhi[j] + (float)vli[j];
            float er = encr[eb + q8 * 8 + j], ei = enci[eb + q8 * 8 + j];
            gr = fmaf(qr, er, fmaf(-qi, ei, gr));
            gi = fmaf(qr, ei, fmaf(qi, er, gi));
        }
    }
    float sr = softr[kk * 8 + h], si = softi[kk * 8 + h];
    float tr = gr * sr - gi * si, ti = gr * si + gi * sr;
    float sn, cs; sincosf(W0 * (float)(kk * i), &sn, &cs);
    ggr[(size_t)z2 * 1024 + i] = tr * cs - ti * sn;
    ggi[(size_t)z2 * 1024 + i] = tr * sn + ti * cs;
}

// ---------------- k_scores: direct-global, 64x128 tile + setprio (T5) ------
__global__ __launch_bounds__(256) void k_scores(
    const h16* __restrict__ khr, const h16* __restrict__ klr,
    const h16* __restrict__ khi, const h16* __restrict__ kli,
    const h16* __restrict__ qhr, const h16* __restrict__ qlr,
    const h16* __restrict__ qhi, const h16* __restrict__ qli,
    const float* __restrict__ ggr, const float* __restrict__ ggi,
    const float* __restrict__ wtc, const float* __restrict__ wts,
    float* __restrict__ S)
{
    __shared__ float T[64][68];  // epilogue transpose (one J-half at a time)

    const int t = threadIdx.x, z = blockIdx.z;
    const int I0 = blockIdx.y * 64, J0 = blockIdx.x * 128;
    const int wave = t >> 6, lane = t & 63, quad = lane >> 4, l16 = lane & 15;
    const int wy = wave >> 1, wx = wave & 1;
    const size_t zb = (size_t)z * 262144;
    const h16* Kp0 = khr + zb; const h16* Kp1 = klr + zb;
    const h16* Kp2 = khi + zb; const h16* Kp3 = kli + zb;
    const h16* Qp0 = qhr + zb; const h16* Qp1 = qlr + zb;
    const h16* Qp2 = qhi + zb; const h16* Qp3 = qli + zb;

    int qo[4];
#pragma unroll
    for (int cc = 0; cc < 4; ++cc)
        qo[cc] = (J0 + (cc >> 1) * 64 + wx * 32 + (cc & 1) * 16 + l16) * 256 + quad * 8;
    const int ko0 = (I0 + wy * 32 + l16) * 256 + quad * 8;
    const int ko1 = ko0 + 16 * 256;

    f4 zero = {0.f, 0.f, 0.f, 0.f};
    f4 Sr[2][4], Si[2][4];
#pragma unroll
    for (int r = 0; r < 2; ++r)
#pragma unroll
        for (int c = 0; c < 4; ++c) { Sr[r][c] = zero; Si[r][c] = zero; }

#pragma unroll
    for (int kq0 = 0; kq0 < 256; kq0 += 32) {
        h8 ahr[2], alr[2], ahi[2], ali[2];
#pragma unroll
        for (int rr = 0; rr < 2; ++rr) {
            const int ko = (rr ? ko1 : ko0) + kq0;
            ahr[rr] = *(const h8*)(Kp0 + ko); alr[rr] = *(const h8*)(Kp1 + ko);
            ahi[rr] = *(const h8*)(Kp2 + ko); ali[rr] = *(const h8*)(Kp3 + ko);
        }
#pragma unroll
        for (int cc = 0; cc < 4; ++cc) {
            h8 bhr = *(const h8*)(Qp0 + qo[cc] + kq0);
            h8 blr = *(const h8*)(Qp1 + qo[cc] + kq0);
            h8 bhi = *(const h8*)(Qp2 + qo[cc] + kq0);
            h8 bli = *(const h8*)(Qp3 + qo[cc] + kq0);
            h8 nbhi = -bhi, nbli = -bli;   // transient; (-a)*b == a*(-b)
            __builtin_amdgcn_s_setprio(1);   // T5: favor MFMA-burst wave
#pragma unroll
            for (int rr = 0; rr < 2; ++rr) {
                Sr[rr][cc] = MFMA16(ahr[rr], bhr, Sr[rr][cc]);
                Sr[rr][cc] = MFMA16(ahr[rr], blr, Sr[rr][cc]);
                Sr[rr][cc] = MFMA16(alr[rr], bhr, Sr[rr][cc]);
                Sr[rr][cc] = MFMA16(ahi[rr], nbhi, Sr[rr][cc]);
                Sr[rr][cc] = MFMA16(ahi[rr], nbli, Sr[rr][cc]);
                Sr[rr][cc] = MFMA16(ali[rr], nbhi, Sr[rr][cc]);
                Si[rr][cc] = MFMA16(ahr[rr], bhi, Si[rr][cc]);
                Si[rr][cc] = MFMA16(ahr[rr], bli, Si[rr][cc]);
                Si[rr][cc] = MFMA16(alr[rr], bhi, Si[rr][cc]);
                Si[rr][cc] = MFMA16(ahi[rr], bhr, Si[rr][cc]);
                Si[rr][cc] = MFMA16(ahi[rr], blr, Si[rr][cc]);
                Si[rr][cc] = MFMA16(ali[rr], bhr, Si[rr][cc]);
            }
            __builtin_amdgcn_s_setprio(0);
        }
    }
    // epilogue: + pos, |.|/8, transpose via LDS, write S[z][j][i]; two J-halves
#pragma unroll
    for (int jh = 0; jh < 2; ++jh) {
        if (jh) __syncthreads();
        float wc2[2][4], ws2[2][4];
#pragma unroll
        for (int c = 0; c < 2; ++c) {
            int j = J0 + jh * 64 + wx * 32 + c * 16 + l16;
#pragma unroll
            for (int k = 0; k < 4; ++k) { wc2[c][k] = wtc[k * 1024 + j]; ws2[c][k] = wts[k * 1024 + j]; }
        }
#pragma unroll
        for (int rr = 0; rr < 2; ++rr)
#pragma unroll
            for (int reg = 0; reg < 4; ++reg) {
                int i = I0 + wy * 32 + rr * 16 + quad * 4 + reg;
                float g_r[4], g_i[4];
#pragma unroll
                for (int k = 0; k < 4; ++k) {
                    g_r[k] = ggr[(size_t)(z * 4 + k) * 1024 + i];
                    g_i[k] = ggi[(size_t)(z * 4 + k) * 1024 + i];
                }
#pragma unroll
                for (int c = 0; c < 2; ++c) {
                    int cc = jh * 2 + c;
                    float pr = 0.f, pi = 0.f;
#pragma unroll
                    for (int k = 0; k < 4; ++k) {
                        pr += g_r[k] * wc2[c][k] + g_i[k] * ws2[c][k];
                        pi += g_i[k] * wc2[c][k] - g_r[k] * ws2[c][k];
                    }
                    float ar = Sr[rr][cc][reg] + pr, ai = Si[rr][cc][reg] + pi;
                    int jl = wx * 32 + c * 16 + l16, il = wy * 32 + rr * 16 + quad * 4 + reg;
                    T[jl][il] = sqrtf(ar * ar + ai * ai) * 0.125f;
                }
            }
        __syncthreads();
        {
            int j2 = t >> 2, ch = (t & 3) * 16;
            float4* Tp = (float4*)&T[j2][ch];
            float4* dst = (float4*)(S + ((size_t)z * 1024 + J0 + jh * 64 + j2) * 1024 + I0 + ch);
#pragma unroll
            for (int w = 0; w < 4; ++w) dst[w] = Tp[w];
        }
    }
}

// ---------------- k_colred: row max, expsum, fp16 Pg plane -----------------
// R21: wave-level __shfl_xor butterflies (exact for max; sum reassociation
// within exercised tolerance). 16 barriers -> 2 per block, 32768 blocks.
__global__ __launch_bounds__(256) void k_colred(
    const float* __restrict__ S, float* __restrict__ cmax, float* __restrict__ csum,
    h16* __restrict__ Pg)
{
    __shared__ float sm[8];
    const int t = threadIdx.x, wave = t >> 6;
    size_t row = blockIdx.x;
    float4 v = ((const float4*)(S + row * 1024))[t];
    float m = fmaxf(fmaxf(v.x, v.y), fmaxf(v.z, v.w));
#pragma unroll
    for (int off = 32; off > 0; off >>= 1) m = fmaxf(m, __shfl_xor(m, off));
    if ((t & 63) == 0) sm[wave] = m;
    __syncthreads();
    float M = fmaxf(fmaxf(sm[0], sm[1]), fmaxf(sm[2], sm[3]));
    float e0 = __expf(v.x - M), e1 = __expf(v.y - M), e2 = __expf(v.z - M), e3 = __expf(v.w - M);
    float e = e0 + e1 + e2 + e3;
#pragma unroll
    for (int off = 32; off > 0; off >>= 1) e += __shfl_xor(e, off);
    if ((t & 63) == 0) sm[4 + wave] = e;
    h4 p; p[0] = (h16)e0; p[1] = (h16)e1; p[2] = (h16)e2; p[3] = (h16)e3;
    *(h4*)(Pg + row * 2048 + t * 4) = p;
    __syncthreads();
    if (t == 0) { cmax[row] = M; csum[row] = sm[4] + sm[5] + sm[6] + sm[7]; }
}

// ---------------- k_qkv_v: V = emb2 @ x (plain fp16 MFMA) ------------------
__global__ __launch_bounds__(256) void k_qkv_v(
    const h16* __restrict__ e2hr, const h16* __restrict__ e2hi,
    const h16* __restrict__ x2hr, const h16* __restrict__ x2hi,
    h16* __restrict__ vr, h16* __restrict__ vi)
{
    __shared__ __align__(16) h16 smem[15360];
    h16* A2[2]; h16* B2[2];
#pragma unroll
    for (int p = 0; p < 2; ++p) { A2[p] = smem + p * 5120; B2[p] = smem + 10240 + p * 2560; }
    const int t = threadIdx.x, bk = blockIdx.z, kk = bk & 3;
    const int N0 = blockIdx.x * 64, D0 = blockIdx.y * 128;
    const int wave = t >> 6, lane = t & 63, quad = lane >> 4, l16 = lane & 15;
    const int wy = wave >> 1, wx = wave & 1;
    const h16* APl[2] = { e2hr + (size_t)kk * 262144, e2hi + (size_t)kk * 262144 };
    const h16* BPl[2] = { x2hr + (size_t)bk * 524288, x2hi + (size_t)bk * 524288 };

    f4 zero = {0.f, 0.f, 0.f, 0.f};
    f4 Rc[4][2], Ic[4][2];
#pragma unroll
    for (int r = 0; r < 4; ++r)
#pragma unroll
        for (int c = 0; c < 2; ++c) { Rc[r][c] = zero; Ic[r][c] = zero; }

    for (int c0 = 0; c0 < Cd; c0 += 32) {
#pragma unroll
        for (int s = 0; s < 3; ++s) {
            int seg = t + 256 * s;
            const h16* src; h16* dst;
            if (seg < 512) {
                int p = seg >> 8, rem = seg & 255, row = rem >> 1, ch = rem & 1;
                src = APl[p] + (size_t)(D0 + row) * 512 + c0 + ch * 16;
                dst = A2[p] + row * 40 + ch * 16;
            } else {
                int s2 = seg - 512, p = s2 >> 7, rem = s2 & 127, row = rem >> 1, ch = rem & 1;
                src = BPl[p] + (size_t)(N0 + row) * 512 + c0 + ch * 16;
                dst = B2[p] + row * 40 + ch * 16;
            }
            const uint4* s4 = (const uint4*)src; uint4 v0 = s4[0], v1 = s4[1];
            uint4* d4 = (uint4*)dst; d4[0] = v0; d4[1] = v1;
        }
        __syncthreads();
        h8 bhr[2], bhi[2];
#pragma unroll
        for (int cc = 0; cc < 2; ++cc) {
            int o = (wx * 32 + cc * 16 + l16) * 40 + quad * 8;
            bhr[cc] = *(const h8*)(B2[0] + o); bhi[cc] = *(const h8*)(B2[1] + o);
        }
#pragma unroll
        for (int rr = 0; rr < 4; ++rr) {
            int o = (wy * 64 + rr * 16 + l16) * 40 + quad * 8;
            h8 ahr = *(const h8*)(A2[0] + o), ahi = *(const h8*)(A2[1] + o);
            h8 nhi = -ahi;
#pragma unroll
            for (int cc = 0; cc < 2; ++cc) {
                Rc[rr][cc] = MFMA16(ahr, bhr[cc], Rc[rr][cc]);
                Rc[rr][cc] = MFMA16(nhi, bhi[cc], Rc[rr][cc]);
                Ic[rr][cc] = MFMA16(ahr, bhi[cc], Ic[rr][cc]);
                Ic[rr][cc] = MFMA16(ahi, bhr[cc], Ic[rr][cc]);
            }
        }
        __syncthreads();
    }
#pragma unroll
    for (int rr = 0; rr < 4; ++rr)
#pragma unroll
        for (int cc = 0; cc < 2; ++cc)
#pragma unroll
            for (int reg = 0; reg < 4; ++reg) {
                int dl = D0 + wy * 64 + rr * 16 + quad * 4 + reg;
                int nl = N0 + wx * 32 + cc * 16 + l16;
                size_t o = (size_t)bk * 524288 + (size_t)dl * 1024 + nl;
                vr[o] = (h16)Rc[rr][cc][reg];
                vi[o] = (h16)Ic[rr][cc][reg];
            }
}

// ---------------- k_ctx: ctx = V @ P, fp16, transposed out -----------------
// R14 structure: staged LDS; P staged from fp16 Pg plane.
__global__ __launch_bounds__(256) void k_ctx(
    const h16* __restrict__ vr, const h16* __restrict__ vi,
    const h16* __restrict__ Pg, const float* __restrict__ csum,
    h16* __restrict__ ctr, h16* __restrict__ cti)
{
    __shared__ __align__(16) h16 Vsr[2560], Vsi[2560], Ps[2560];
    __shared__ __align__(16) h16 T2[4608];  // 64 x 72
    const int t = threadIdx.x, z = blockIdx.z, kk = blockIdx.y, M0 = blockIdx.x * 64;
    const int b = z >> 3, h = z & 7;
    const int wave = t >> 6, lane = t & 63, quad = lane >> 4, l16 = lane & 15;
    const int wy = wave >> 1, wx = wave & 1;
    const size_t vbase = (size_t)(b * 4 + kk) * 524288 + (size_t)(h * 64) * 1024;
    const size_t pbase = (size_t)(z * 1024 + M0);

    f4 zero = {0.f, 0.f, 0.f, 0.f};
    f4 accR[2][2], accI[2][2];
#pragma unroll
    for (int r = 0; r < 2; ++r)
#pragma unroll
        for (int c = 0; c < 2; ++c) { accR[r][c] = zero; accI[r][c] = zero; }

    for (int i0 = 0; i0 < 1024; i0 += 32) {
        if (t < 128) {
            int comp = t >> 6, q = t & 63;
            const h16* src = (comp ? vi : vr) + vbase + (size_t)q * 1024 + i0;
            h16* dst = (comp ? Vsi : Vsr) + q * 40;
            const uint4* s4 = (const uint4*)src;
#pragma unroll
            for (int w = 0; w < 4; ++w) ((uint4*)dst)[w] = s4[w];
        } else {
            int tt = t - 128, m = tt >> 1, ch = tt & 1;
            const h16* sp = Pg + (pbase + m) * 2048 + i0 + ch * 16;
            h16* dst = Ps + m * 40 + ch * 16;
            ((uint4*)dst)[0] = ((const uint4*)sp)[0];
            ((uint4*)dst)[1] = ((const uint4*)sp)[1];
        }
        __syncthreads();
        h8 bp[2];
#pragma unroll
        for (int cc = 0; cc < 2; ++cc)
            bp[cc] = *(const h8*)(Ps + (wx * 32 + cc * 16 + l16) * 40 + quad * 8);
#pragma unroll
        for (int rr = 0; rr < 2; ++rr) {
            int o = (wy * 32 + rr * 16 + l16) * 40 + quad * 8;
            h8 avr = *(const h8*)(Vsr + o), avi = *(const h8*)(Vsi + o);
#pragma unroll
            for (int cc = 0; cc < 2; ++cc) {
                accR[rr][cc] = MFMA16(avr, bp[cc], accR[rr][cc]);
                accI[rr][cc] = MFMA16(avi, bp[cc], accI[rr][cc]);
            }
        }
        __syncthreads();
    }
    for (int round = 0; round < 2; ++round) {
#pragma unroll
        for (int rr = 0; rr < 2; ++rr)
#pragma unroll
            for (int cc = 0; cc < 2; ++cc) {
                int ml = wx * 32 + cc * 16 + l16;
                float inv = 1.0f / csum[(size_t)z * 1024 + M0 + ml];
#pragma unroll
                for (int reg = 0; reg < 4; ++reg) {
                    int ql = wy * 32 + rr * 16 + quad * 4 + reg;
                    float v = (round ? accI[rr][cc][reg] : accR[rr][cc][reg]) * inv;
                    T2[ml * 72 + ql] = (h16)v;
                }
            }
        __syncthreads();
        {
            int m = t >> 2, ch = (t & 3) * 16;
            h8 v0 = *(const h8*)(T2 + m * 72 + ch), v1 = *(const h8*)(T2 + m * 72 + ch + 8);
            h16* dst = (round ? cti : ctr) + (size_t)(b * 4 + kk) * 524288 + (size_t)(M0 + m) * 512 + h * 64 + ch;
            *(h8*)dst = v0; *(h8*)(dst + 8) = v1;
        }
        __syncthreads();
    }
}

// ---------------- k_out: res = Re(out @ ctx), MFMA fp16 --------------------
__global__ __launch_bounds__(256) void k_out(
    const float* __restrict__ outr, const float* __restrict__ outi,
    const h16* __restrict__ ctr, const h16* __restrict__ cti,
    float* __restrict__ res)
{
    __shared__ __align__(16) h16 smem[10240];
    h16* Asr; h16* Asi; h16* Bsr; h16* Bsi;
    Asr = smem; Asi = smem + 2560; Bsr = smem + 5120; Bsi = smem + 7680;
    const int t = threadIdx.x, bk = blockIdx.z, kk = bk & 3;
    const int N0 = blockIdx.x * 64, D0 = blockIdx.y * 64;
    const int wave = t >> 6, lane = t & 63, quad = lane >> 4, l16 = lane & 15;
    const int wy = wave >> 1, wx = wave & 1;

    f4 zero = {0.f, 0.f, 0.f, 0.f};
    f4 P1[2][2], P2[2][2];
#pragma unroll
    for (int r = 0; r < 2; ++r)
#pragma unroll
        for (int c = 0; c < 2; ++c) { P1[r][c] = zero; P2[r][c] = zero; }

    for (int c0 = 0; c0 < Cd; c0 += 32) {
        {   // stage A: out fp32 -> fp16
            int comp = t >> 7, rem = t & 127, row = rem >> 1, ch = rem & 1;
            const float4* sp = (const float4*)((comp ? outi : outr) + (size_t)kk * 262144 + (size_t)(D0 + row) * 512 + c0 + ch * 16);
            h8 h0v, h1v;
#pragma unroll
            for (int w = 0; w < 4; ++w) {
                float4 v = sp[w];
                h16 a = (h16)v.x, b2 = (h16)v.y, c = (h16)v.z, d = (h16)v.w;
                if (w < 2) { h0v[w*4] = a; h0v[w*4+1] = b2; h0v[w*4+2] = c; h0v[w*4+3] = d; }
                else { h1v[(w-2)*4] = a; h1v[(w-2)*4+1] = b2; h1v[(w-2)*4+2] = c; h1v[(w-2)*4+3] = d; }
            }
            h16* dst = (comp ? Asi : Asr) + row * 40 + ch * 16;
            *(h8*)dst = h0v; *(h8*)(dst + 8) = h1v;
        }
        {   // stage B: ctx_t fp16 copy
            int comp = t >> 7, rem = t & 127, row = rem >> 1, ch = rem & 1;
            const h16* src = (comp ? cti : ctr) + (size_t)bk * 524288 + (size_t)(N0 + row) * 512 + c0 + ch * 16;
            h16* dst = (comp ? Bsi : Bsr) + row * 40 + ch * 16;
            const uint4* s4 = (const uint4*)src; uint4 v0 = s4[0], v1 = s4[1];
            uint4* d4 = (uint4*)dst; d4[0] = v0; d4[1] = v1;
        }
        __syncthreads();
        h8 br[2], bi[2];
#pragma unroll
        for (int cc = 0; cc < 2; ++cc) {
            int o = (wx * 32 + cc * 16 + l16) * 40 + quad * 8;
            br[cc] = *(const h8*)(Bsr + o); bi[cc] = *(const h8*)(Bsi + o);
        }
#pragma unroll
        for (int rr = 0; rr < 2; ++rr) {
            int o = (wy * 32 + rr * 16 + l16) * 40 + quad * 8;
            h8 ar = *(const h8*)(Asr + o), ai = *(const h8*)(Asi + o);
#pragma unroll
            for (int cc = 0; cc < 2; ++cc) {
                P1[rr][cc] = MFMA16(ar, br[cc], P1[rr][cc]);
                P2[rr][cc] = MFMA16(ai, bi[cc], P2[rr][cc]);
            }
        }
        __syncthreads();
    }
#pragma unroll
    for (int rr = 0; rr < 2; ++rr)
#pragma unroll
        for (int cc = 0; cc < 2; ++cc)
#pragma unroll
            for (int reg = 0; reg < 4; ++reg) {
                int dl = D0 + wy * 32 + rr * 16 + quad * 4 + reg;
                int nl = N0 + wx * 32 + cc * 16 + l16;
                res[(size_t)bk * 524288 + (size_t)dl * 1024 + nl] = P1[rr][cc][reg] - P2[rr][cc][reg];
            }
}

extern "C" void kernel_launch(void* const* d_in, const int* in_sizes, int n_in,
                              void* d_out, int out_size, void* d_ws, size_t ws_size,
                              hipStream_t stream)
{
    const float* xr    = (const float*)d_in[0];
    const float* xi    = (const float*)d_in[1];
    const float* embr  = (const float*)d_in[2];
    const float* embi  = (const float*)d_in[3];
    const float* encr  = (const float*)d_in[4];
    const float* enci  = (const float*)d_in[5];
    const float* softr = (const float*)d_in[6];
    const float* softi = (const float*)d_in[7];
    const float* outr  = (const float*)d_in[8];
    const float* outi  = (const float*)d_in[9];
    float* res = (float*)d_out;
    char* ws   = (char*)d_ws;
    if (ws_size < (size_t)268435456) return;

    h16* qhr = (h16*)(ws + QHR); h16* qlr = (h16*)(ws + QLR);
    h16* qhi = (h16*)(ws + QHI); h16* qli = (h16*)(ws + QLI);
    h16* khr = (h16*)(ws + KHR); h16* klr = (h16*)(ws + KLR);
    h16* khi = (h16*)(ws + KHI); h16* kli = (h16*)(ws + KLI);
    float* S  = (float*)(ws + SOFF);
    h16* Pg   = (h16*)(ws + SOFF);   // fp16 P plane aliases S rows (row-aligned)
    h16* xthr = (h16*)(ws + XTHR); h16* xtlr = (h16*)(ws + XTLR);
    h16* xthi = (h16*)(ws + XTHI); h16* xtli = (h16*)(ws + XTLI);
    h16* ehr = (h16*)(ws + EHR); h16* elr = (h16*)(ws + ELR);
    h16* ehi = (h16*)(ws + EHI); h16* eli = (h16*)(ws + ELI);
    h16* x2hr = (h16*)(ws + X2HR); h16* x2hi = (h16*)(ws + X2HI);
    h16* e2hr = (h16*)(ws + E2HR); h16* e2hi = (h16*)(ws + E2HI);
    h16* vr = (h16*)(ws + VRO); h16* vi = (h16*)(ws + VIO);
    h16* ctr = (h16*)(ws + CTR); h16* cti = (h16*)(ws + CTI);
    float* sc = (float*)d_out;  // scratch in d_out, overwritten by k_out last
    float* ggr = sc + GG_R; float* ggi = sc + GG_I;
    float* wtc = sc + WT_C; float* wts = sc + WT_S;
    float* cmax = sc + CMAX; float* csum = sc + CSUM;

    k_prep_x<0><<<dim3(16, 8, 16), 256, 0, stream>>>(xr, xi, xthr, xtlr, xthi, xtli);
    k_prep_emb<0><<<dim3(2048), 256, 0, stream>>>(embr, embi, 0, ehr, elr, ehi, eli);
    k_wtab<<<dim3(16), 256, 0, stream>>>(wtc, wts);
    k_qkv01<<<dim3(16, 4, 32), 256, 0, stream>>>(ehr, elr, ehi, eli, xthr, xtlr, xthi, xtli,
                                                 qhr, qlr, qhi, qli, khr, klr, khi, kli, softr, softi);
    k_gg<<<dim3(4, 128), 256, 0, stream>>>(qhr, qlr, qhi, qli, encr, enci, softr, softi, ggr, ggi);
    k_scores<<<dim3(8, 16, 32), 256, 0, stream>>>(khr, klr, khi, kli, qhr, qlr, qhi, qli,
                                                  ggr, ggi, wtc, wts, S);
    k_colred<<<dim3(32768), 256, 0, stream>>>(S, cmax, csum, Pg);
    k_prep_x<1><<<dim3(16, 8, 16), 256, 0, stream>>>(xr, xi, x2hr, x2hr, x2hi, x2hi);
    k_prep_emb<1><<<dim3(1024), 256, 0, stream>>>(embr, embi, 2097152, e2hr, e2hr, e2hi, e2hi);
    k_qkv_v<<<dim3(16, 4, 16), 256, 0, stream>>>(e2hr, e2hi, x2hr, x2hi, vr, vi);
    k_ctx<<<dim3(16, 4, 32), 256, 0, stream>>>(vr, vi, Pg, csum, ctr, cti);
    k_out<<<dim3(16, 8, 16), 256, 0, stream>>>(outr, outi, ctr, cti, res);
}